// Round 2
// baseline (109.061 us; speedup 1.0000x reference)
//
#include <hip/hip_runtime.h>

typedef _Float16 h2 __attribute__((ext_vector_type(2)));
typedef _Float16 h8 __attribute__((ext_vector_type(8)));
typedef __fp16   g2 __attribute__((ext_vector_type(2)));
typedef float    v4f __attribute__((ext_vector_type(4)));

namespace {
constexpr int BATCH = 4;
constexpr int IN_N  = 32;
constexpr int OUT_N = 32;
constexpr int H_IN  = 28;     // input spatial
constexpr int HW    = 26;     // output spatial (28-3+1)
constexpr int NI    = 288;    // IN_N * 3 * 3
constexpr int D     = 16;
constexpr int ITERS = 7;
constexpr float INV_SCALE = 1.0f / 3.0f;   // 1/(sqrt(16) * 0.75)
constexpr float EPS = 1e-5f;

constexpr int VH_S = 16;      // sVh row stride (halves, 32 B); granule-XOR swizzled
constexpr int AT_S = 296;     // sAt row stride (halves, 592 B): 16B-aligned b128 rows
constexpr int P_S  = 36;      // step-5 partial stride (floats)

// DPP ctrl encodings
constexpr int DPP_XOR1 = 0xB1;   // quad_perm [1,0,3,2]
constexpr int DPP_XOR2 = 0x4E;   // quad_perm [2,3,0,1]
constexpr int DPP_HMIR = 0x141;  // row_half_mirror (xor-ish swap across 4-lane halves of 8)
constexpr int DPP_ROR4 = 0x124;  // row rotate 4 (within 16)
constexpr int DPP_ROR8 = 0x128;  // row rotate 8 == xor8 within 16
}

union H8U { h2 q[4]; h8 v; int2 i2[2]; };

static __device__ __forceinline__ int h2bits(h2 x) { union { h2 h; int i; } u; u.h = x; return u.i; }

// cvt_pkrtz returns __fp16x2; bit-cast to our _Float16-based h2
static __device__ __forceinline__ h2 pkrtz(float a, float b) {
  union { g2 g; h2 h; } u;
  u.g = __builtin_amdgcn_cvt_pkrtz(a, b);
  return u.h;
}

static __device__ __forceinline__ float dot2f(h2 a, h2 b, float c) {
#if __has_builtin(__builtin_amdgcn_fdot2)
  return __builtin_amdgcn_fdot2(a, b, c, false);
#else
  return c + (float)a.x * (float)b.x + (float)a.y * (float)b.y;
#endif
}

// x + dpp_perm(x): cross-lane add on the VALU pipe (no ds_bpermute)
template <int CTRL>
static __device__ __forceinline__ float dpp_add(float x) {
  union { float f; int i; } s, r;
  s.f = x;
  r.i = __builtin_amdgcn_update_dpp(s.i, s.i, CTRL, 0xF, 0xF, false);
  return x + r.f;
}

extern "C" __global__ __launch_bounds__(256, 5)
void capsule_fused(const float* __restrict__ input,
                   const float* __restrict__ w_current,
                   const float* __restrict__ w_next,
                   const float* __restrict__ ln_scale,
                   const float* __restrict__ ln_bias,
                   float* __restrict__ out) {
  // Manual LDS carving: 32512 B total -> rounds to 32768 -> 5 blocks/CU (was 4).
  __shared__ __align__(16) unsigned char smem[32512];
  _Float16* sVh  = (_Float16*)(smem);            // [288][16] halves, granule-swizzled (9216 B)
  float*    Pf   = (float*)(smem);               // overlay: step-5 partials [4][16][36] (9216 B)
  _Float16* sAt  = (_Float16*)(smem + 9216);     // A^T [32][296] halves (18944 B)
  _Float16* sQtT = (_Float16*)(smem + 28160);    // fp16 w_next[o][d] * INV_SCALE (1024 B)
  float*    sU   = (float*)(smem + 29184);       // u[0..287], v[288..319] (1280 B)
  float*    sScr = (float*)(smem + 30464);       // sinkhorn ping-pong [2][4][32] / np [16][32] (2048 B)

  const int t   = threadIdx.x;
  const int l   = t & 63;
  const int wv  = t >> 6;
  const int bid = blockIdx.x;
  const int b   = bid / (HW * HW);
  const int sp  = bid % (HW * HW);
  const int hh  = sp / HW;
  const int ww  = sp % HW;

  H8U zu; zu.i2[0] = make_int2(0, 0); zu.i2[1] = make_int2(0, 0);
  const h8 zero8 = zu.v;

  // stage fp16 qf: sQtT[o][d] = fp16(w_next[o][d] / 3)   (256 h2 pairs, one pass)
  {
    const int o = t >> 3, dp = t & 7;
    const float a0 = w_next[o * 16 + 2 * dp]     * INV_SCALE;
    const float a1 = w_next[o * 16 + 2 * dp + 1] * INV_SCALE;
    *(h2*)(sQtT + o * 16 + 2 * dp) = pkrtz(a0, a1);
  }

  // ---- step 1: V[i][p*4+r] = sum_q pose[p][q]*w_current[q][r]; store f16 swizzled ----
  // swizzle: halves h of row i live at i*16 + 8*((h>>3) ^ ((i>>3)&1)) + (h&7)
  for (int i = t; i < NI; i += 256) {
    const int n = i / 9, kl = i % 9, ky = kl / 3, kx = kl % 3;
    const float* px = input + (((b * IN_N + n) * H_IN + (hh + ky)) * H_IN + (ww + kx)) * D;
    float p[16], wt[16];
    *(float4*)(p +  0) = *(const float4*)(px +  0);
    *(float4*)(p +  4) = *(const float4*)(px +  4);
    *(float4*)(p +  8) = *(const float4*)(px +  8);
    *(float4*)(p + 12) = *(const float4*)(px + 12);
    const float* wc = w_current + (kl * IN_N + n) * 16;
    *(float4*)(wt +  0) = *(const float4*)(wc +  0);
    *(float4*)(wt +  4) = *(const float4*)(wc +  4);
    *(float4*)(wt +  8) = *(const float4*)(wc +  8);
    *(float4*)(wt + 12) = *(const float4*)(wc + 12);
    float vv[16];
    #pragma unroll
    for (int pp = 0; pp < 4; ++pp)
      #pragma unroll
      for (int rr = 0; rr < 4; ++rr)
        vv[pp * 4 + rr] = p[pp*4+0]*wt[0+rr] + p[pp*4+1]*wt[4+rr]
                        + p[pp*4+2]*wt[8+rr] + p[pp*4+3]*wt[12+rr];
    H8U lo, hi;
    #pragma unroll
    for (int jj = 0; jj < 4; ++jj) {
      lo.q[jj] = pkrtz(vv[2*jj],     vv[2*jj + 1]);
      hi.q[jj] = pkrtz(vv[8 + 2*jj], vv[8 + 2*jj + 1]);
    }
    const int flip8 = ((i >> 3) & 1) * 8;
    *(h8*)(sVh + i * VH_S + flip8)       = lo.v;
    *(h8*)(sVh + i * VH_S + (flip8 ^ 8)) = hi.v;
  }
  __syncthreads();

  // ---- step 2: A^T[o][i] = exp(Vf[i].qf[o]/3) via MFMA 16x16x32 (K zero-padded) ----
  {
    const int lo16 = l & 15;
    const int q4   = l >> 4;          // k-quad
    const int kq   = (q4 & 1) * 8;    // real k base for quads 0,1
    const bool hiK = (q4 >= 2);       // quads 2,3 = zero-pad region (k>=16)
    h8 bf[2];
    #pragma unroll
    for (int nt = 0; nt < 2; ++nt) {
      const int o = lo16 + 16 * nt;
      bf[nt] = hiK ? zero8 : *(const h8*)(sQtT + o * 16 + kq);   // halves kq..kq+7 of row o
    }
    // sVh read granule offset is a per-lane constant: 8*((kq>>3) ^ ((m>>3)&1)) with
    // (m>>3)&1 == (lo16>>3)&1 since m = mt*16 + lo16
    const int vflip = 8 * ((q4 & 1) ^ ((lo16 >> 3) & 1));
    for (int mt = wv; mt < 18; mt += 4) {
      const int m = mt * 16 + lo16;
      h8 af = zero8;
      if (!hiK) af = *(const h8*)(sVh + m * VH_S + vflip);
      #pragma unroll
      for (int nt = 0; nt < 2; ++nt) {
        v4f acc = {0.f, 0.f, 0.f, 0.f};
        acc = __builtin_amdgcn_mfma_f32_16x16x32_f16(af, bf[nt], acc, 0, 0, 0);
        // D: col(o-within-tile)=l&15, row(i-offset)=4*q4+reg
        const int o  = lo16 + 16 * nt;
        const int ib = mt * 16 + 4 * q4;
        h2 p0 = pkrtz(__expf(acc[0]), __expf(acc[1]));
        h2 p1 = pkrtz(__expf(acc[2]), __expf(acc[3]));
        int2 wr; wr.x = h2bits(p0); wr.y = h2bits(p1);
        *(int2*)(sAt + o * AT_S + ib) = wr;   // A^T[o][ib..ib+3]
      }
    }
  }
  __syncthreads();

  // ---- step 3: Sinkhorn in registers, RESCALED (v-step = 8/colsum; exact x0.375 comp later).
  // One barrier per iteration: in-wave col reduce (DPP ror8 + shfl_xor 16/32), 4x32 partials
  // ping-ponged in sScr, then every thread gathers its own 4 columns and computes v in regs.
  const int c4 = t & 7;
  const int hq = t >> 3;
  h2 A2a[9], A2b[9];
  {
    const _Float16* r0 = sAt + (4*c4 + 0) * AT_S + 9 * hq;
    const _Float16* r1 = sAt + (4*c4 + 1) * AT_S + 9 * hq;
    const _Float16* r2 = sAt + (4*c4 + 2) * AT_S + 9 * hq;
    const _Float16* r3 = sAt + (4*c4 + 3) * AT_S + 9 * hq;
    #pragma unroll
    for (int j = 0; j < 9; ++j) {
      h2 a; a.x = r0[j]; a.y = r1[j]; A2a[j] = a;
      h2 c; c.x = r2[j]; c.y = r3[j]; A2b[j] = c;
    }
  }
  float ureg[9];
  h2 v2a = pkrtz(1.0f, 1.0f);
  h2 v2b = v2a;
  for (int it = 0; it < ITERS; ++it) {
    // u-pass: row sums over o; reduce across the 8 c4-lanes via DPP (xor1,xor2,half-mirror)
    #pragma unroll
    for (int j = 0; j < 9; ++j) {
      float s = dot2f(A2b[j], v2b, dot2f(A2a[j], v2a, 0.f));
      s = dpp_add<DPP_XOR1>(s);
      s = dpp_add<DPP_XOR2>(s);
      s = dpp_add<DPP_HMIR>(s);
      ureg[j] = __builtin_amdgcn_rcpf(s);
    }
    // col-pass: fp32 partial col sums over this thread's 9 i's
    float sca = 0.f, scb = 0.f, scc = 0.f, scd = 0.f;
    #pragma unroll
    for (int j = 0; j < 9; ++j) {
      const float uj = ureg[j];
      sca += (float)A2a[j].x * uj;
      scb += (float)A2a[j].y * uj;
      scc += (float)A2b[j].x * uj;
      scd += (float)A2b[j].y * uj;
    }
    // full in-wave reduce over the 8 hq-slices (lane strides 8, 16, 32)
    sca = dpp_add<DPP_ROR8>(sca);
    scb = dpp_add<DPP_ROR8>(scb);
    scc = dpp_add<DPP_ROR8>(scc);
    scd = dpp_add<DPP_ROR8>(scd);
    sca += __shfl_xor(sca, 16); scb += __shfl_xor(scb, 16);
    scc += __shfl_xor(scc, 16); scd += __shfl_xor(scd, 16);
    sca += __shfl_xor(sca, 32); scb += __shfl_xor(scb, 32);
    scc += __shfl_xor(scc, 32); scd += __shfl_xor(scd, 32);
    float* buf = sScr + (it & 1) * 128;   // ping-pong: safe with ONE barrier/iter
    if (l < 8) {
      v4f w4; w4[0] = sca; w4[1] = scb; w4[2] = scc; w4[3] = scd;
      *(v4f*)(buf + wv * 32 + l * 4) = w4;   // [wave][o]
    }
    __syncthreads();
    // every thread gathers its own 4 o-columns (broadcast reads) and computes v in regs
    const v4f g0 = *(const v4f*)(buf + 0 * 32 + 4 * c4);
    const v4f g1 = *(const v4f*)(buf + 1 * 32 + 4 * c4);
    const v4f g2 = *(const v4f*)(buf + 2 * 32 + 4 * c4);
    const v4f g3 = *(const v4f*)(buf + 3 * 32 + 4 * c4);
    const v4f S4 = g0 + g1 + g2 + g3;
    const float va = 8.0f * __builtin_amdgcn_rcpf(S4[0]);
    const float vb = 8.0f * __builtin_amdgcn_rcpf(S4[1]);
    const float vc = 8.0f * __builtin_amdgcn_rcpf(S4[2]);
    const float vd = 8.0f * __builtin_amdgcn_rcpf(S4[3]);
    v2a = pkrtz(va, vb);
    v2b = pkrtz(vc, vd);
    if (it == ITERS - 1 && t < 8) {        // t==c4, hq==0: publish final v for the combine
      v4f vw; vw[0] = va; vw[1] = vb; vw[2] = vc; vw[3] = vd;
      *(v4f*)(sU + NI + 4 * t) = vw;
    }
  }
  if (c4 == 0) {
    #pragma unroll
    for (int j = 0; j < 9; ++j) sU[9 * hq + j] = ureg[j];
  }
  __syncthreads();

  // ---- step 5: np~[o][d] = sum_k A^T[o][k] * (u_k * V[k][d]) via MFMA 16x16x32 ----
  v4f acc5_0 = {0.f, 0.f, 0.f, 0.f};
  v4f acc5_1 = {0.f, 0.f, 0.f, 0.f};
  {
    const int d  = l & 15;
    const int q4 = l >> 4;
    // swizzled half offset for column d of row r: 8*((d>>3) ^ ((r>>3)&1)) + (d&7);
    // (r>>3)&1 == q4&1 for all rows r = kt*32 + q4*8 + z (z<8) -> per-lane constant
    const int doff = 8 * ((d >> 3) ^ (q4 & 1)) + (d & 7);
    for (int kt = wv; kt < 9; kt += 4) {
      const int kg = kt * 32 + q4 * 8;
      const v4f ua = *(const v4f*)(sU + kg);
      const v4f ub = *(const v4f*)(sU + kg + 4);
      float uu[8];
      #pragma unroll
      for (int z = 0; z < 4; ++z) { uu[z] = ua[z]; uu[4 + z] = ub[z]; }
      H8U bu;
      #pragma unroll
      for (int jj = 0; jj < 4; ++jj) {
        const float b0 = (float)sVh[(kg + 2*jj)     * VH_S + doff] * uu[2*jj];
        const float b1 = (float)sVh[(kg + 2*jj + 1) * VH_S + doff] * uu[2*jj + 1];
        bu.q[jj] = pkrtz(b0, b1);
      }
      const h8 af0 = *(const h8*)(sAt + d * AT_S        + kt * 32 + q4 * 8);
      const h8 af1 = *(const h8*)(sAt + (16 + d) * AT_S + kt * 32 + q4 * 8);
      acc5_0 = __builtin_amdgcn_mfma_f32_16x16x32_f16(af0, bu.v, acc5_0, 0, 0, 0);
      acc5_1 = __builtin_amdgcn_mfma_f32_16x16x32_f16(af1, bu.v, acc5_1, 0, 0, 0);
    }
  }
  __syncthreads();   // all sVh/sAt reads done -> safe to overlay P into sVh
  {
    const int d = l & 15, q4 = l >> 4;
    // D: col=d, row(o-offset)=4*q4+reg
    *(v4f*)(Pf + (wv * 16 + d) * P_S + 0  + 4 * q4) = acc5_0;
    *(v4f*)(Pf + (wv * 16 + d) * P_S + 16 + 4 * q4) = acc5_1;
  }
  __syncthreads();
  // combine K-partials; np*3 = S~ * v~_o * (3/8)  (the /8 undoes the v rescale)
  #pragma unroll
  for (int pass = 0; pass < 2; ++pass) {
    const int e = t + 256 * pass;
    const int o = e & 31, dd = e >> 5;
    const float S = Pf[(0 * 16 + dd) * P_S + o] + Pf[(1 * 16 + dd) * P_S + o]
                  + Pf[(2 * 16 + dd) * P_S + o] + Pf[(3 * 16 + dd) * P_S + o];
    sScr[dd * 32 + o] = S * 0.375f * sU[NI + o];
  }
  __syncthreads();

  // ---- step 6: out[o][p*4+r] = sum_q np[o][p*4+q]*w_next[o][q*4+r]; LayerNorm over d ----
  {
    float vals[2];
    #pragma unroll
    for (int h2p = 0; h2p < 2; ++h2p) {
      const int e = t + h2p * 256;
      const int o = e >> 4, dd = e & 15;
      const int pp = dd >> 2, rr = dd & 3;
      float acc = 0.f;
      #pragma unroll
      for (int q = 0; q < 4; ++q)
        acc += sScr[(pp * 4 + q) * 32 + o] * (float)sQtT[o * 16 + q * 4 + rr];
      vals[h2p] = acc;
    }
    // LN over the 16 d's: full-16 DPP reduction (quad sums, then rotate-4/8)
    float s0 = vals[0], q0 = vals[0] * vals[0];
    float s1 = vals[1], q1 = vals[1] * vals[1];
    s0 = dpp_add<DPP_XOR1>(s0); q0 = dpp_add<DPP_XOR1>(q0);
    s1 = dpp_add<DPP_XOR1>(s1); q1 = dpp_add<DPP_XOR1>(q1);
    s0 = dpp_add<DPP_XOR2>(s0); q0 = dpp_add<DPP_XOR2>(q0);
    s1 = dpp_add<DPP_XOR2>(s1); q1 = dpp_add<DPP_XOR2>(q1);
    s0 = dpp_add<DPP_ROR4>(s0); q0 = dpp_add<DPP_ROR4>(q0);
    s1 = dpp_add<DPP_ROR4>(s1); q1 = dpp_add<DPP_ROR4>(q1);
    s0 = dpp_add<DPP_ROR8>(s0); q0 = dpp_add<DPP_ROR8>(q0);
    s1 = dpp_add<DPP_ROR8>(s1); q1 = dpp_add<DPP_ROR8>(q1);
    #pragma unroll
    for (int h2p = 0; h2p < 2; ++h2p) {
      const int e = t + h2p * 256;
      const int o = e >> 4, dd = e & 15;
      const float ss = h2p ? s1 : s0;
      const float qq = h2p ? q1 : q0;
      const float mu   = ss * (1.0f / 16.0f);
      const float var  = qq * (1.0f / 16.0f) - mu * mu;
      const float rstd = rsqrtf(var + EPS);
      const float y = (vals[h2p] - mu) * rstd * ln_scale[dd] + ln_bias[dd];
      out[(((b * OUT_N + o) * HW + hh) * HW + ww) * D + dd] = y;
    }
  }
}

extern "C" void kernel_launch(void* const* d_in, const int* in_sizes, int n_in,
                              void* d_out, int out_size, void* d_ws, size_t ws_size,
                              hipStream_t stream) {
  const float* input     = (const float*)d_in[0];
  const float* w_current = (const float*)d_in[1];
  const float* w_next    = (const float*)d_in[2];
  const float* ln_scale  = (const float*)d_in[3];
  const float* ln_bias   = (const float*)d_in[4];
  float* outp = (float*)d_out;

  dim3 grid(BATCH * HW * HW);   // 2704 blocks, one per (b, h, w)
  dim3 block(256);
  capsule_fused<<<grid, block, 0, stream>>>(input, w_current, w_next,
                                            ln_scale, ln_bias, outp);
}

// Round 4
// 98.774 us; speedup vs baseline: 1.1042x; 1.1042x over previous
//
#include <hip/hip_runtime.h>

typedef _Float16 h2 __attribute__((ext_vector_type(2)));
typedef _Float16 h8 __attribute__((ext_vector_type(8)));
typedef __fp16   g2 __attribute__((ext_vector_type(2)));
typedef float    v4f __attribute__((ext_vector_type(4)));

namespace {
constexpr int BATCH = 4;
constexpr int IN_N  = 32;
constexpr int OUT_N = 32;
constexpr int H_IN  = 28;     // input spatial
constexpr int HW    = 26;     // output spatial (28-3+1)
constexpr int NI    = 288;    // IN_N * 3 * 3
constexpr int D     = 16;
constexpr int ITERS = 7;
constexpr float INV_SCALE = 1.0f / 3.0f;   // 1/(sqrt(16) * 0.75)
constexpr float EPS = 1e-5f;

constexpr int VH_S = 16;      // sVh row stride (halves, 32 B); granule-XOR swizzled
constexpr int AT_S = 296;     // sAt row stride (halves, 592 B): 16B-aligned b128 rows
constexpr int P_S  = 36;      // step-5 partial stride (floats)

// DPP ctrl encodings
constexpr int DPP_XOR1 = 0xB1;   // quad_perm [1,0,3,2]
constexpr int DPP_XOR2 = 0x4E;   // quad_perm [2,3,0,1]
constexpr int DPP_ROR4 = 0x124;  // row rotate 4 (within 16)
constexpr int DPP_ROR8 = 0x128;  // row rotate 8 == xor8 within 16
}

union H8U { h2 q[4]; h8 v; int2 i2[2]; };

static __device__ __forceinline__ int h2bits(h2 x) { union { h2 h; int i; } u; u.h = x; return u.i; }

// cvt_pkrtz returns __fp16x2; bit-cast to our _Float16-based h2
static __device__ __forceinline__ h2 pkrtz(float a, float b) {
  union { g2 g; h2 h; } u;
  u.g = __builtin_amdgcn_cvt_pkrtz(a, b);
  return u.h;
}

static __device__ __forceinline__ float dot2f(h2 a, h2 b, float c) {
#if __has_builtin(__builtin_amdgcn_fdot2)
  return __builtin_amdgcn_fdot2(a, b, c, false);
#else
  return c + (float)a.x * (float)b.x + (float)a.y * (float)b.y;
#endif
}

// x + dpp_perm(x): cross-lane add on the VALU pipe (no ds_bpermute)
template <int CTRL>
static __device__ __forceinline__ float dpp_add(float x) {
  union { float f; int i; } s, r;
  s.f = x;
  r.i = __builtin_amdgcn_update_dpp(s.i, s.i, CTRL, 0xF, 0xF, false);
  return x + r.f;
}

extern "C" __global__ __launch_bounds__(256, 4)
void capsule_fused(const float* __restrict__ input,
                   const float* __restrict__ w_current,
                   const float* __restrict__ w_next,
                   const float* __restrict__ ln_scale,
                   const float* __restrict__ ln_bias,
                   float* __restrict__ out) {
  // Manual LDS carving: 32512 B total.
  __shared__ __align__(16) unsigned char smem[32512];
  _Float16* sVh  = (_Float16*)(smem);            // [288][16] halves, granule-swizzled (9216 B)
  float*    Pf   = (float*)(smem);               // overlay: step-5 partials [4][16][36] (9216 B)
  _Float16* sAt  = (_Float16*)(smem + 9216);     // A^T [32][296] halves (18944 B)
  _Float16* sQtT = (_Float16*)(smem + 28160);    // fp16 w_next[o][d] * INV_SCALE (1024 B)
  float*    sU   = (float*)(smem + 29184);       // fp32 finals: u[0..287], v[288..319] (1280 B)
  float*    sScr = (float*)(smem + 30464);       // step3 scratch / np [16][32] (2048 B)
  // step-3 carving of sScr:
  float*    Pw   = sScr;                          // col-sum partials [4 waves][32 o] (512 B)
  _Float16* sUh  = (_Float16*)((unsigned char*)sScr + 512);   // u f16 [288] (576 B, 16B-aligned)
  _Float16* sVf  = (_Float16*)((unsigned char*)sScr + 1088);  // v f16 [32] (64 B, 16B-aligned)

  const int t   = threadIdx.x;
  const int l   = t & 63;
  const int wv  = t >> 6;
  const int bid = blockIdx.x;
  const int b   = bid / (HW * HW);
  const int sp  = bid % (HW * HW);
  const int hh  = sp / HW;
  const int ww  = sp % HW;

  H8U zu; zu.i2[0] = make_int2(0, 0); zu.i2[1] = make_int2(0, 0);
  const h8 zero8 = zu.v;

  // stage fp16 qf: sQtT[o][d] = fp16(w_next[o][d] / 3)   (256 h2 pairs, one pass)
  {
    const int o = t >> 3, dp = t & 7;
    const float a0 = w_next[o * 16 + 2 * dp]     * INV_SCALE;
    const float a1 = w_next[o * 16 + 2 * dp + 1] * INV_SCALE;
    *(h2*)(sQtT + o * 16 + 2 * dp) = pkrtz(a0, a1);
  }

  // ---- step 1: V[i][p*4+r] = sum_q pose[p][q]*w_current[q][r]; store f16 swizzled ----
  // swizzle: halves h of row i live at i*16 + 8*((h>>3) ^ ((i>>3)&1)) + (h&7)
  for (int i = t; i < NI; i += 256) {
    const int n = i / 9, kl = i % 9, ky = kl / 3, kx = kl % 3;
    const float* px = input + (((b * IN_N + n) * H_IN + (hh + ky)) * H_IN + (ww + kx)) * D;
    float p[16], wt[16];
    *(float4*)(p +  0) = *(const float4*)(px +  0);
    *(float4*)(p +  4) = *(const float4*)(px +  4);
    *(float4*)(p +  8) = *(const float4*)(px +  8);
    *(float4*)(p + 12) = *(const float4*)(px + 12);
    const float* wc = w_current + (kl * IN_N + n) * 16;
    *(float4*)(wt +  0) = *(const float4*)(wc +  0);
    *(float4*)(wt +  4) = *(const float4*)(wc +  4);
    *(float4*)(wt +  8) = *(const float4*)(wc +  8);
    *(float4*)(wt + 12) = *(const float4*)(wc + 12);
    float vv[16];
    #pragma unroll
    for (int pp = 0; pp < 4; ++pp)
      #pragma unroll
      for (int rr = 0; rr < 4; ++rr)
        vv[pp * 4 + rr] = p[pp*4+0]*wt[0+rr] + p[pp*4+1]*wt[4+rr]
                        + p[pp*4+2]*wt[8+rr] + p[pp*4+3]*wt[12+rr];
    H8U lo, hi;
    #pragma unroll
    for (int jj = 0; jj < 4; ++jj) {
      lo.q[jj] = pkrtz(vv[2*jj],     vv[2*jj + 1]);
      hi.q[jj] = pkrtz(vv[8 + 2*jj], vv[8 + 2*jj + 1]);
    }
    const int flip8 = ((i >> 3) & 1) * 8;
    *(h8*)(sVh + i * VH_S + flip8)       = lo.v;
    *(h8*)(sVh + i * VH_S + (flip8 ^ 8)) = hi.v;
  }
  __syncthreads();

  // ---- step 2: A^T[o][i] = exp(Vf[i].qf[o]/3) via MFMA 16x16x32 (K zero-padded) ----
  {
    const int lo16 = l & 15;
    const int q4   = l >> 4;          // k-quad
    const int kq   = (q4 & 1) * 8;    // real k base for quads 0,1
    const bool hiK = (q4 >= 2);       // quads 2,3 = zero-pad region (k>=16)
    h8 bf[2];
    #pragma unroll
    for (int nt = 0; nt < 2; ++nt) {
      const int o = lo16 + 16 * nt;
      bf[nt] = hiK ? zero8 : *(const h8*)(sQtT + o * 16 + kq);   // halves kq..kq+7 of row o
    }
    const int vflip = 8 * ((q4 & 1) ^ ((lo16 >> 3) & 1));
    for (int mt = wv; mt < 18; mt += 4) {
      const int m = mt * 16 + lo16;
      h8 af = zero8;
      if (!hiK) af = *(const h8*)(sVh + m * VH_S + vflip);
      #pragma unroll
      for (int nt = 0; nt < 2; ++nt) {
        v4f acc = {0.f, 0.f, 0.f, 0.f};
        acc = __builtin_amdgcn_mfma_f32_16x16x32_f16(af, bf[nt], acc, 0, 0, 0);
        // D: col(o-within-tile)=l&15, row(i-offset)=4*q4+reg
        const int o  = lo16 + 16 * nt;
        const int ib = mt * 16 + 4 * q4;
        h2 p0 = pkrtz(__expf(acc[0]), __expf(acc[1]));
        h2 p1 = pkrtz(__expf(acc[2]), __expf(acc[3]));
        int2 wr; wr.x = h2bits(p0); wr.y = h2bits(p1);
        *(int2*)(sAt + o * AT_S + ib) = wr;   // A^T[o][ib..ib+3]
      }
    }
  }
  __syncthreads();

  // ---- step 3: Sinkhorn, minimum-VALU form.
  // u-pass: row-per-thread, 16 fdot2, no cross-lane. col-pass: A^T u on the MFMA pipe
  // with u broadcast into all 16 B-columns (every lane reads the same h8 of u).
  // v rescaled: v = 8/colsum (exact x0.375 compensation in the combine after step 5).
  {
    const int lo16 = l & 15;
    const int q4   = l >> 4;
    // preload A-row for row i=t (and i=t+32 for t>=224): strided u16 reads, one-time.
    // Arow[oo] = (A[i][2oo], A[i][2oo+1])
    h2 Arow[16];
    {
      const _Float16* colp = sAt + t;
      #pragma unroll
      for (int oo = 0; oo < 16; ++oo) {
        h2 a; a.x = colp[(2*oo) * AT_S]; a.y = colp[(2*oo + 1) * AT_S];
        Arow[oo] = a;
      }
    }
    h2 Arow2[16];
    if (t >= 224) {
      const _Float16* colp = sAt + (t + 32);
      #pragma unroll
      for (int oo = 0; oo < 16; ++oo) {
        h2 a; a.x = colp[(2*oo) * AT_S]; a.y = colp[(2*oo + 1) * AT_S];
        Arow2[oo] = a;
      }
    }

    for (int it = 0; it < ITERS; ++it) {
      // v fragments: v-pairs (v[2j],v[2j+1]); iter 0 = ones
      H8U va, vb, vc, vd;
      if (it == 0) {
        const h2 one2 = pkrtz(1.0f, 1.0f);
        #pragma unroll
        for (int jj = 0; jj < 4; ++jj) { va.q[jj] = one2; vb.q[jj] = one2; vc.q[jj] = one2; vd.q[jj] = one2; }
      } else {
        va.v = *(const h8*)(sVf);        // v[0..7]
        vb.v = *(const h8*)(sVf + 8);    // v[8..15]
        vc.v = *(const h8*)(sVf + 16);   // v[16..23]
        vd.v = *(const h8*)(sVf + 24);   // v[24..31]
      }
      // u-pass: row sums, fully in-lane (16 fdot2, fp32 accum)
      float s0 = 0.f, s1 = 0.f;
      #pragma unroll
      for (int oo = 0; oo < 4; ++oo) {
        s0 = dot2f(Arow[oo],      va.q[oo], s0);
        s0 = dot2f(Arow[4 + oo],  vb.q[oo], s0);
        s1 = dot2f(Arow[8 + oo],  vc.q[oo], s1);
        s1 = dot2f(Arow[12 + oo], vd.q[oo], s1);
      }
      const float u = __builtin_amdgcn_rcpf(s0 + s1);
      sUh[t] = (_Float16)u;
      if (it == ITERS - 1) sU[t] = u;
      if (t >= 224) {
        float e0 = 0.f, e1 = 0.f;
        #pragma unroll
        for (int oo = 0; oo < 4; ++oo) {
          e0 = dot2f(Arow2[oo],      va.q[oo], e0);
          e0 = dot2f(Arow2[4 + oo],  vb.q[oo], e0);
          e1 = dot2f(Arow2[8 + oo],  vc.q[oo], e1);
          e1 = dot2f(Arow2[12 + oo], vd.q[oo], e1);
        }
        const float u2 = __builtin_amdgcn_rcpf(e0 + e1);
        sUh[t + 32] = (_Float16)u2;
        if (it == ITERS - 1) sU[t + 32] = u2;
      }
      __syncthreads();   // BAR A: sUh complete

      // col-pass: acc[o] = sum_k A^T[o][k] u[k] on MFMA; waves split the 9 k-steps
      v4f acc0 = {0.f, 0.f, 0.f, 0.f};
      v4f acc1 = {0.f, 0.f, 0.f, 0.f};
      for (int ks = wv; ks < 9; ks += 4) {
        const int kb = ks * 32 + q4 * 8;
        const h8 uf  = *(const h8*)(sUh + kb);                 // B[k][n]=u[k] for all n (broadcast)
        const h8 af0 = *(const h8*)(sAt + lo16 * AT_S + kb);
        const h8 af1 = *(const h8*)(sAt + (16 + lo16) * AT_S + kb);
        acc0 = __builtin_amdgcn_mfma_f32_16x16x32_f16(af0, uf, acc0, 0, 0, 0);
        acc1 = __builtin_amdgcn_mfma_f32_16x16x32_f16(af1, uf, acc1, 0, 0, 0);
      }
      // D cols all equal; rows o = tile*16 + 4*q4 + reg. One lane-group writes.
      if (lo16 == 0) {
        *(v4f*)(Pw + wv * 32 + 0  + 4 * q4) = acc0;
        *(v4f*)(Pw + wv * 32 + 16 + 4 * q4) = acc1;
      }
      __syncthreads();   // BAR B: Pw complete (also: all sUh reads done)

      if (t < 32) {
        const float S = Pw[0 * 32 + t] + Pw[1 * 32 + t] + Pw[2 * 32 + t] + Pw[3 * 32 + t];
        const float v = 8.0f * __builtin_amdgcn_rcpf(S);
        sVf[t] = (_Float16)v;
        if (it == ITERS - 1) sU[NI + t] = v;   // fp32 final v
      }
      __syncthreads();   // BAR C: sVf ready for next u-pass (and Pw reads done)
    }
  }

  // ---- step 5: np~[o][d] = sum_k A^T[o][k] * (u_k * V[k][d]) via MFMA 16x16x32 ----
  v4f acc5_0 = {0.f, 0.f, 0.f, 0.f};
  v4f acc5_1 = {0.f, 0.f, 0.f, 0.f};
  {
    const int d  = l & 15;
    const int q4 = l >> 4;
    // swizzled half offset for column d of row r: 8*((d>>3) ^ ((r>>3)&1)) + (d&7);
    // (r>>3)&1 == q4&1 for all rows r = kt*32 + q4*8 + z (z<8) -> per-lane constant
    const int doff = 8 * ((d >> 3) ^ (q4 & 1)) + (d & 7);
    for (int kt = wv; kt < 9; kt += 4) {
      const int kg = kt * 32 + q4 * 8;
      const v4f ua = *(const v4f*)(sU + kg);
      const v4f ub = *(const v4f*)(sU + kg + 4);
      float uu[8];
      #pragma unroll
      for (int z = 0; z < 4; ++z) { uu[z] = ua[z]; uu[4 + z] = ub[z]; }
      H8U bu;
      #pragma unroll
      for (int jj = 0; jj < 4; ++jj) {
        const float b0 = (float)sVh[(kg + 2*jj)     * VH_S + doff] * uu[2*jj];
        const float b1 = (float)sVh[(kg + 2*jj + 1) * VH_S + doff] * uu[2*jj + 1];
        bu.q[jj] = pkrtz(b0, b1);
      }
      const h8 af0 = *(const h8*)(sAt + d * AT_S        + kt * 32 + q4 * 8);
      const h8 af1 = *(const h8*)(sAt + (16 + d) * AT_S + kt * 32 + q4 * 8);
      acc5_0 = __builtin_amdgcn_mfma_f32_16x16x32_f16(af0, bu.v, acc5_0, 0, 0, 0);
      acc5_1 = __builtin_amdgcn_mfma_f32_16x16x32_f16(af1, bu.v, acc5_1, 0, 0, 0);
    }
  }
  __syncthreads();   // all sVh/sAt reads done -> safe to overlay P into sVh
  {
    const int d = l & 15, q4 = l >> 4;
    // D: col=d, row(o-offset)=4*q4+reg
    *(v4f*)(Pf + (wv * 16 + d) * P_S + 0  + 4 * q4) = acc5_0;
    *(v4f*)(Pf + (wv * 16 + d) * P_S + 16 + 4 * q4) = acc5_1;
  }
  __syncthreads();
  // combine K-partials; np*3 = S~ * v~_o * (3/8)  (the /8 undoes the v rescale)
  #pragma unroll
  for (int pass = 0; pass < 2; ++pass) {
    const int e = t + 256 * pass;
    const int o = e & 31, dd = e >> 5;
    const float S = Pf[(0 * 16 + dd) * P_S + o] + Pf[(1 * 16 + dd) * P_S + o]
                  + Pf[(2 * 16 + dd) * P_S + o] + Pf[(3 * 16 + dd) * P_S + o];
    sScr[dd * 32 + o] = S * 0.375f * sU[NI + o];
  }
  __syncthreads();

  // ---- step 6: out[o][p*4+r] = sum_q np[o][p*4+q]*w_next[o][q*4+r]; LayerNorm over d ----
  {
    float vals[2];
    #pragma unroll
    for (int h2p = 0; h2p < 2; ++h2p) {
      const int e = t + h2p * 256;
      const int o = e >> 4, dd = e & 15;
      const int pp = dd >> 2, rr = dd & 3;
      float acc = 0.f;
      #pragma unroll
      for (int q = 0; q < 4; ++q)
        acc += sScr[(pp * 4 + q) * 32 + o] * (float)sQtT[o * 16 + q * 4 + rr];
      vals[h2p] = acc;
    }
    // LN over the 16 d's: full-16 DPP reduction (quad sums, then rotate-4/8)
    float s0 = vals[0], q0 = vals[0] * vals[0];
    float s1 = vals[1], q1 = vals[1] * vals[1];
    s0 = dpp_add<DPP_XOR1>(s0); q0 = dpp_add<DPP_XOR1>(q0);
    s1 = dpp_add<DPP_XOR1>(s1); q1 = dpp_add<DPP_XOR1>(q1);
    s0 = dpp_add<DPP_XOR2>(s0); q0 = dpp_add<DPP_XOR2>(q0);
    s1 = dpp_add<DPP_XOR2>(s1); q1 = dpp_add<DPP_XOR2>(q1);
    s0 = dpp_add<DPP_ROR4>(s0); q0 = dpp_add<DPP_ROR4>(q0);
    s1 = dpp_add<DPP_ROR4>(s1); q1 = dpp_add<DPP_ROR4>(q1);
    s0 = dpp_add<DPP_ROR8>(s0); q0 = dpp_add<DPP_ROR8>(q0);
    s1 = dpp_add<DPP_ROR8>(s1); q1 = dpp_add<DPP_ROR8>(q1);
    #pragma unroll
    for (int h2p = 0; h2p < 2; ++h2p) {
      const int e = t + h2p * 256;
      const int o = e >> 4, dd = e & 15;
      const float ss = h2p ? s1 : s0;
      const float qq = h2p ? q1 : q0;
      const float mu   = ss * (1.0f / 16.0f);
      const float var  = qq * (1.0f / 16.0f) - mu * mu;
      const float rstd = rsqrtf(var + EPS);
      const float y = (vals[h2p] - mu) * rstd * ln_scale[dd] + ln_bias[dd];
      out[(((b * OUT_N + o) * HW + hh) * HW + ww) * D + dd] = y;
    }
  }
}

extern "C" void kernel_launch(void* const* d_in, const int* in_sizes, int n_in,
                              void* d_out, int out_size, void* d_ws, size_t ws_size,
                              hipStream_t stream) {
  const float* input     = (const float*)d_in[0];
  const float* w_current = (const float*)d_in[1];
  const float* w_next    = (const float*)d_in[2];
  const float* ln_scale  = (const float*)d_in[3];
  const float* ln_bias   = (const float*)d_in[4];
  float* outp = (float*)d_out;

  dim3 grid(BATCH * HW * HW);   // 2704 blocks, one per (b, h, w)
  dim3 block(256);
  capsule_fused<<<grid, block, 0, stream>>>(input, w_current, w_next,
                                            ln_scale, ln_bias, outp);
}

// Round 8
// 97.064 us; speedup vs baseline: 1.1236x; 1.0176x over previous
//
#include <hip/hip_runtime.h>

typedef _Float16 h2 __attribute__((ext_vector_type(2)));
typedef _Float16 h8 __attribute__((ext_vector_type(8)));
typedef __fp16   g2 __attribute__((ext_vector_type(2)));
typedef float    v4f __attribute__((ext_vector_type(4)));

namespace {
constexpr int BATCH = 4;
constexpr int IN_N  = 32;
constexpr int OUT_N = 32;
constexpr int H_IN  = 28;     // input spatial
constexpr int HW    = 26;     // output spatial (28-3+1)
constexpr int NI    = 288;    // IN_N * 3 * 3
constexpr int D     = 16;
constexpr int ITERS = 7;
// 1/(sqrt(16)*0.75) * log2(e): exp(x/3) == exp2(x * SCALE_L2E).
constexpr float SCALE_L2E = 0.48089834696298783f;
// Combine constant: 0.375 * ln2. Step 6 multiplies by sQtT = w*(log2e/3), so the
// total is np*3*ln2 * w*log2e/3 = np*w EXACTLY (ln2*log2e == 1). Do NOT rely on
// "uniform scale cancels in LayerNorm" -- it fails when var ~ EPS (measured r5/r6:
// absmax 0.43 from EPS-dominated rows amplifying the residual scale by ~1/sqrt(EPS)).
constexpr float COMB_C = 0.375f * 0.69314718055994531f;
constexpr float EPS = 1e-5f;

constexpr int VH_S = 16;      // sVh row stride (halves, 32 B); granule-XOR swizzled
constexpr int AT_S = 296;     // sAt row stride (halves, 592 B): 16B-aligned b128 rows
constexpr int P_S  = 36;      // step-5 partial stride (floats)

// DPP ctrl encodings
constexpr int DPP_XOR1 = 0xB1;   // quad_perm [1,0,3,2]
constexpr int DPP_XOR2 = 0x4E;   // quad_perm [2,3,0,1]
constexpr int DPP_ROR4 = 0x124;  // row rotate 4 (within 16)
constexpr int DPP_ROR8 = 0x128;  // row rotate 8 == xor8 within 16
}

union H8U { h2 q[4]; h8 v; int2 i2[2]; };

static __device__ __forceinline__ int h2bits(h2 x) { union { h2 h; int i; } u; u.h = x; return u.i; }

// cvt_pkrtz returns __fp16x2; bit-cast to our _Float16-based h2
static __device__ __forceinline__ h2 pkrtz(float a, float b) {
  union { g2 g; h2 h; } u;
  u.g = __builtin_amdgcn_cvt_pkrtz(a, b);
  return u.h;
}

static __device__ __forceinline__ float dot2f(h2 a, h2 b, float c) {
#if __has_builtin(__builtin_amdgcn_fdot2)
  return __builtin_amdgcn_fdot2(a, b, c, false);
#else
  return c + (float)a.x * (float)b.x + (float)a.y * (float)b.y;
#endif
}

static __device__ __forceinline__ float exp2_fast(float x) {
#if __has_builtin(__builtin_amdgcn_exp2f)
  return __builtin_amdgcn_exp2f(x);      // bare v_exp_f32 (computes 2^x)
#else
  return __expf(x * 0.6931471805599453f);
#endif
}

// x + dpp_perm(x): cross-lane add on the VALU pipe (no ds_bpermute)
template <int CTRL>
static __device__ __forceinline__ float dpp_add(float x) {
  union { float f; int i; } s, r;
  s.f = x;
  r.i = __builtin_amdgcn_update_dpp(s.i, s.i, CTRL, 0xF, 0xF, false);
  return x + r.f;
}

extern "C" __global__ __launch_bounds__(256, 4)
void capsule_fused(const float* __restrict__ input,
                   const float* __restrict__ w_current,
                   const float* __restrict__ w_next,
                   const float* __restrict__ ln_scale,
                   const float* __restrict__ ln_bias,
                   float* __restrict__ out) {
  // Manual LDS carving: 32512 B total.
  __shared__ __align__(16) unsigned char smem[32512];
  _Float16* sVh  = (_Float16*)(smem);            // [288][16] halves, granule-swizzled (9216 B)
  float*    Pf   = (float*)(smem);               // overlay: step-5 partials [4][16][36] (9216 B)
  _Float16* sAt  = (_Float16*)(smem + 9216);     // A^T [32][296] halves (18944 B)
  _Float16* sQtT = (_Float16*)(smem + 28160);    // fp16 w_next[o][d] * SCALE_L2E (1024 B)
  float*    sU   = (float*)(smem + 29184);       // fp32 finals: v[NI..NI+31] (1280 B region)
  float*    sScr = (float*)(smem + 30464);       // step3 scratch / np [16][32] (2048 B)
  // step-3 carving of sScr:
  float*    Pw   = sScr;                          // col-sum partials [4 waves][32 o] (512 B)
  _Float16* sUh  = (_Float16*)((unsigned char*)sScr + 512);   // u f16 [288] (576 B, 16B-aligned)
  _Float16* sVf  = (_Float16*)((unsigned char*)sScr + 1088);  // v f16 [32] (64 B, 16B-aligned)

  const int t   = threadIdx.x;
  const int l   = t & 63;
  const int wv  = t >> 6;
  const int bid = blockIdx.x;
  const int b   = bid / (HW * HW);
  const int sp  = bid % (HW * HW);
  const int hh  = sp / HW;
  const int ww  = sp % HW;

  H8U zu; zu.i2[0] = make_int2(0, 0); zu.i2[1] = make_int2(0, 0);
  const h8 zero8 = zu.v;

  // stage fp16 qf: sQtT[o][d] = fp16(w_next[o][d] * SCALE_L2E)   (256 h2 pairs, one pass)
  {
    const int o = t >> 3, dp = t & 7;
    const float a0 = w_next[o * 16 + 2 * dp]     * SCALE_L2E;
    const float a1 = w_next[o * 16 + 2 * dp + 1] * SCALE_L2E;
    *(h2*)(sQtT + o * 16 + 2 * dp) = pkrtz(a0, a1);
  }

  // ---- step 1: V[i][p*4+r] = sum_q pose[p][q]*w_current[q][r]; store f16 swizzled ----
  // swizzle: halves h of row i live at i*16 + 8*((h>>3) ^ ((i>>3)&1)) + (h&7)
  for (int i = t; i < NI; i += 256) {
    const int n = i / 9, kl = i % 9, ky = kl / 3, kx = kl % 3;
    const float* px = input + (((b * IN_N + n) * H_IN + (hh + ky)) * H_IN + (ww + kx)) * D;
    float p[16], wt[16];
    *(float4*)(p +  0) = *(const float4*)(px +  0);
    *(float4*)(p +  4) = *(const float4*)(px +  4);
    *(float4*)(p +  8) = *(const float4*)(px +  8);
    *(float4*)(p + 12) = *(const float4*)(px + 12);
    const float* wc = w_current + (kl * IN_N + n) * 16;
    *(float4*)(wt +  0) = *(const float4*)(wc +  0);
    *(float4*)(wt +  4) = *(const float4*)(wc +  4);
    *(float4*)(wt +  8) = *(const float4*)(wc +  8);
    *(float4*)(wt + 12) = *(const float4*)(wc + 12);
    float vv[16];
    #pragma unroll
    for (int pp = 0; pp < 4; ++pp)
      #pragma unroll
      for (int rr = 0; rr < 4; ++rr)
        vv[pp * 4 + rr] = p[pp*4+0]*wt[0+rr] + p[pp*4+1]*wt[4+rr]
                        + p[pp*4+2]*wt[8+rr] + p[pp*4+3]*wt[12+rr];
    H8U lo, hi;
    #pragma unroll
    for (int jj = 0; jj < 4; ++jj) {
      lo.q[jj] = pkrtz(vv[2*jj],     vv[2*jj + 1]);
      hi.q[jj] = pkrtz(vv[8 + 2*jj], vv[8 + 2*jj + 1]);
    }
    const int flip8 = ((i >> 3) & 1) * 8;
    *(h8*)(sVh + i * VH_S + flip8)       = lo.v;
    *(h8*)(sVh + i * VH_S + (flip8 ^ 8)) = hi.v;
  }
  __syncthreads();

  // ---- step 2: A^T[o][i] = exp2(Vf[i].qf_l2e[o]) via MFMA 16x16x32 (K zero-padded) ----
  {
    const int lo16 = l & 15;
    const int q4   = l >> 4;          // k-quad
    const int kq   = (q4 & 1) * 8;    // real k base for quads 0,1
    const bool hiK = (q4 >= 2);       // quads 2,3 = zero-pad region (k>=16)
    h8 bf[2];
    #pragma unroll
    for (int nt = 0; nt < 2; ++nt) {
      const int o = lo16 + 16 * nt;
      bf[nt] = hiK ? zero8 : *(const h8*)(sQtT + o * 16 + kq);   // halves kq..kq+7 of row o
    }
    const int vflip = 8 * ((q4 & 1) ^ ((lo16 >> 3) & 1));
    for (int mt = wv; mt < 18; mt += 4) {
      const int m = mt * 16 + lo16;
      h8 af = zero8;
      if (!hiK) af = *(const h8*)(sVh + m * VH_S + vflip);
      #pragma unroll
      for (int nt = 0; nt < 2; ++nt) {
        v4f acc = {0.f, 0.f, 0.f, 0.f};
        acc = __builtin_amdgcn_mfma_f32_16x16x32_f16(af, bf[nt], acc, 0, 0, 0);
        // D: col(o-within-tile)=l&15, row(i-offset)=4*q4+reg
        const int o  = lo16 + 16 * nt;
        const int ib = mt * 16 + 4 * q4;
        h2 p0 = pkrtz(exp2_fast(acc[0]), exp2_fast(acc[1]));
        h2 p1 = pkrtz(exp2_fast(acc[2]), exp2_fast(acc[3]));
        int2 wr; wr.x = h2bits(p0); wr.y = h2bits(p1);
        *(int2*)(sAt + o * AT_S + ib) = wr;   // A^T[o][ib..ib+3]
      }
    }
  }
  __syncthreads();

  // ---- step 3: Sinkhorn, minimum-VALU form.
  // u-pass: row-per-thread, 16 fdot2, no cross-lane. col-pass: A^T u on the MFMA pipe
  // with u broadcast into all 16 B-columns (every lane reads the same h8 of u).
  // v rescaled: v = 8/colsum (exact compensation via COMB_C in the combine).
  {
    const int lo16 = l & 15;
    const int q4   = l >> 4;
    // preload A-row for row i=t (and i=t+32 for t>=224): strided u16 reads, one-time.
    // Arow[oo] = (A[i][2oo], A[i][2oo+1])
    h2 Arow[16];
    {
      const _Float16* colp = sAt + t;
      #pragma unroll
      for (int oo = 0; oo < 16; ++oo) {
        h2 a; a.x = colp[(2*oo) * AT_S]; a.y = colp[(2*oo + 1) * AT_S];
        Arow[oo] = a;
      }
    }
    h2 Arow2[16];
    if (t >= 224) {
      const _Float16* colp = sAt + (t + 32);
      #pragma unroll
      for (int oo = 0; oo < 16; ++oo) {
        h2 a; a.x = colp[(2*oo) * AT_S]; a.y = colp[(2*oo + 1) * AT_S];
        Arow2[oo] = a;
      }
    }

    for (int it = 0; it < ITERS; ++it) {
      // v fragments: v-pairs (v[2j],v[2j+1]); iter 0 = ones
      H8U va, vb, vc, vd;
      if (it == 0) {
        const h2 one2 = pkrtz(1.0f, 1.0f);
        #pragma unroll
        for (int jj = 0; jj < 4; ++jj) { va.q[jj] = one2; vb.q[jj] = one2; vc.q[jj] = one2; vd.q[jj] = one2; }
      } else {
        va.v = *(const h8*)(sVf);        // v[0..7]
        vb.v = *(const h8*)(sVf + 8);    // v[8..15]
        vc.v = *(const h8*)(sVf + 16);   // v[16..23]
        vd.v = *(const h8*)(sVf + 24);   // v[24..31]
      }
      // u-pass: row sums, fully in-lane (16 fdot2, fp32 accum)
      float s0 = 0.f, s1 = 0.f;
      #pragma unroll
      for (int oo = 0; oo < 4; ++oo) {
        s0 = dot2f(Arow[oo],      va.q[oo], s0);
        s0 = dot2f(Arow[4 + oo],  vb.q[oo], s0);
        s1 = dot2f(Arow[8 + oo],  vc.q[oo], s1);
        s1 = dot2f(Arow[12 + oo], vd.q[oo], s1);
      }
      const float u = __builtin_amdgcn_rcpf(s0 + s1);
      sUh[t] = (_Float16)u;
      if (t >= 224) {
        float e0 = 0.f, e1 = 0.f;
        #pragma unroll
        for (int oo = 0; oo < 4; ++oo) {
          e0 = dot2f(Arow2[oo],      va.q[oo], e0);
          e0 = dot2f(Arow2[4 + oo],  vb.q[oo], e0);
          e1 = dot2f(Arow2[8 + oo],  vc.q[oo], e1);
          e1 = dot2f(Arow2[12 + oo], vd.q[oo], e1);
        }
        const float u2 = __builtin_amdgcn_rcpf(e0 + e1);
        sUh[t + 32] = (_Float16)u2;
      }
      __syncthreads();   // BAR A: sUh complete

      // col-pass: acc[o] = sum_k A^T[o][k] u[k] on MFMA; waves split the 9 k-steps
      v4f acc0 = {0.f, 0.f, 0.f, 0.f};
      v4f acc1 = {0.f, 0.f, 0.f, 0.f};
      for (int ks = wv; ks < 9; ks += 4) {
        const int kb = ks * 32 + q4 * 8;
        const h8 uf  = *(const h8*)(sUh + kb);                 // B[k][n]=u[k] for all n (broadcast)
        const h8 af0 = *(const h8*)(sAt + lo16 * AT_S + kb);
        const h8 af1 = *(const h8*)(sAt + (16 + lo16) * AT_S + kb);
        acc0 = __builtin_amdgcn_mfma_f32_16x16x32_f16(af0, uf, acc0, 0, 0, 0);
        acc1 = __builtin_amdgcn_mfma_f32_16x16x32_f16(af1, uf, acc1, 0, 0, 0);
      }
      // D cols all equal; rows o = tile*16 + 4*q4 + reg. One lane-group writes.
      if (lo16 == 0) {
        *(v4f*)(Pw + wv * 32 + 0  + 4 * q4) = acc0;
        *(v4f*)(Pw + wv * 32 + 16 + 4 * q4) = acc1;
      }
      __syncthreads();   // BAR B: Pw complete (also: all sUh reads done)

      if (t < 32) {
        const float S = Pw[0 * 32 + t] + Pw[1 * 32 + t] + Pw[2 * 32 + t] + Pw[3 * 32 + t];
        const float v = 8.0f * __builtin_amdgcn_rcpf(S);
        sVf[t] = (_Float16)v;
        if (it == ITERS - 1) sU[NI + t] = v;   // fp32 final v
      }
      __syncthreads();   // BAR C: sVf ready for next u-pass (and Pw reads done)
    }
  }

  // ---- step 5: np~[o][d] = sum_k (A^T[o][k]*u_k) * V[k][d] via MFMA 16x16x32 ----
  // u folded into the A-operand with v_pk_mul_f16 (u from sUh, final-iter f16 values);
  // B-fragment is raw f16 pair-assembly from sVh (zero VALU beyond the pack).
  v4f acc5_0 = {0.f, 0.f, 0.f, 0.f};
  v4f acc5_1 = {0.f, 0.f, 0.f, 0.f};
  {
    const int d  = l & 15;
    const int q4 = l >> 4;
    // swizzled half offset for column d of row r: 8*((d>>3) ^ ((r>>3)&1)) + (d&7);
    // (r>>3)&1 == q4&1 for all rows r = kt*32 + q4*8 + z (z<8) -> per-lane constant
    const int doff = 8 * ((d >> 3) ^ (q4 & 1)) + (d & 7);
    for (int kt = wv; kt < 9; kt += 4) {
      const int kg = kt * 32 + q4 * 8;
      H8U uu; uu.v = *(const h8*)(sUh + kg);                 // u[kg..kg+7] f16 (broadcast)
      H8U a0; a0.v = *(const h8*)(sAt + d * AT_S        + kg);
      H8U a1; a1.v = *(const h8*)(sAt + (16 + d) * AT_S + kg);
      H8U a0u, a1u;
      #pragma unroll
      for (int jj = 0; jj < 4; ++jj) {
        a0u.q[jj] = a0.q[jj] * uu.q[jj];                     // v_pk_mul_f16
        a1u.q[jj] = a1.q[jj] * uu.q[jj];
      }
      H8U bu;
      #pragma unroll
      for (int jj = 0; jj < 4; ++jj) {
        h2 bq;
        bq.x = sVh[(kg + 2*jj)     * VH_S + doff];
        bq.y = sVh[(kg + 2*jj + 1) * VH_S + doff];
        bu.q[jj] = bq;
      }
      acc5_0 = __builtin_amdgcn_mfma_f32_16x16x32_f16(a0u.v, bu.v, acc5_0, 0, 0, 0);
      acc5_1 = __builtin_amdgcn_mfma_f32_16x16x32_f16(a1u.v, bu.v, acc5_1, 0, 0, 0);
    }
  }
  __syncthreads();   // all sVh/sAt/sUh reads done -> safe to overlay P into sVh
  {
    const int d = l & 15, q4 = l >> 4;
    // D: col=d, row(o-offset)=4*q4+reg
    *(v4f*)(Pf + (wv * 16 + d) * P_S + 0  + 4 * q4) = acc5_0;
    *(v4f*)(Pf + (wv * 16 + d) * P_S + 16 + 4 * q4) = acc5_1;
  }
  __syncthreads();
  // combine K-partials: sScr = np*3*ln2 = S~ * v~_o * (3/8)*ln2.
  // (the /8 undoes the v rescale; ln2 cancels sQtT's log2e in step 6 EXACTLY)
  #pragma unroll
  for (int pass = 0; pass < 2; ++pass) {
    const int e = t + 256 * pass;
    const int o = e & 31, dd = e >> 5;
    const float S = Pf[(0 * 16 + dd) * P_S + o] + Pf[(1 * 16 + dd) * P_S + o]
                  + Pf[(2 * 16 + dd) * P_S + o] + Pf[(3 * 16 + dd) * P_S + o];
    sScr[dd * 32 + o] = S * COMB_C * sU[NI + o];
  }
  __syncthreads();

  // ---- step 6: out[o][p*4+r] = sum_q np[o][p*4+q]*w_next[o][q*4+r]; LayerNorm over d ----
  // np*3*ln2 times w_next*(log2e/3) == np*w_next exactly -> EPS-consistent LN.
  {
    float vals[2];
    #pragma unroll
    for (int h2p = 0; h2p < 2; ++h2p) {
      const int e = t + h2p * 256;
      const int o = e >> 4, dd = e & 15;
      const int pp = dd >> 2, rr = dd & 3;
      float acc = 0.f;
      #pragma unroll
      for (int q = 0; q < 4; ++q)
        acc += sScr[(pp * 4 + q) * 32 + o] * (float)sQtT[o * 16 + q * 4 + rr];
      vals[h2p] = acc;
    }
    // LN over the 16 d's: full-16 DPP reduction (quad sums, then rotate-4/8)
    float s0 = vals[0], q0 = vals[0] * vals[0];
    float s1 = vals[1], q1 = vals[1] * vals[1];
    s0 = dpp_add<DPP_XOR1>(s0); q0 = dpp_add<DPP_XOR1>(q0);
    s1 = dpp_add<DPP_XOR1>(s1); q1 = dpp_add<DPP_XOR1>(q1);
    s0 = dpp_add<DPP_XOR2>(s0); q0 = dpp_add<DPP_XOR2>(q0);
    s1 = dpp_add<DPP_XOR2>(s1); q1 = dpp_add<DPP_XOR2>(q1);
    s0 = dpp_add<DPP_ROR4>(s0); q0 = dpp_add<DPP_ROR4>(q0);
    s1 = dpp_add<DPP_ROR4>(s1); q1 = dpp_add<DPP_ROR4>(q1);
    s0 = dpp_add<DPP_ROR8>(s0); q0 = dpp_add<DPP_ROR8>(q0);
    s1 = dpp_add<DPP_ROR8>(s1); q1 = dpp_add<DPP_ROR8>(q1);
    #pragma unroll
    for (int h2p = 0; h2p < 2; ++h2p) {
      const int e = t + h2p * 256;
      const int o = e >> 4, dd = e & 15;
      const float ss = h2p ? s1 : s0;
      const float qq = h2p ? q1 : q0;
      const float mu   = ss * (1.0f / 16.0f);
      const float var  = qq * (1.0f / 16.0f) - mu * mu;
      const float rstd = rsqrtf(var + EPS);
      const float y = (vals[h2p] - mu) * rstd * ln_scale[dd] + ln_bias[dd];
      out[(((b * OUT_N + o) * HW + hh) * HW + ww) * D + dd] = y;
    }
  }
}

extern "C" void kernel_launch(void* const* d_in, const int* in_sizes, int n_in,
                              void* d_out, int out_size, void* d_ws, size_t ws_size,
                              hipStream_t stream) {
  const float* input     = (const float*)d_in[0];
  const float* w_current = (const float*)d_in[1];
  const float* w_next    = (const float*)d_in[2];
  const float* ln_scale  = (const float*)d_in[3];
  const float* ln_bias   = (const float*)d_in[4];
  float* outp = (float*)d_out;

  dim3 grid(BATCH * HW * HW);   // 2704 blocks, one per (b, h, w)
  dim3 block(256);
  capsule_fused<<<grid, block, 0, stream>>>(input, w_current, w_next,
                                            ln_scale, ln_bias, outp);
}

// Round 9
// 96.825 us; speedup vs baseline: 1.1264x; 1.0025x over previous
//
#include <hip/hip_runtime.h>

typedef _Float16 h2 __attribute__((ext_vector_type(2)));
typedef _Float16 h8 __attribute__((ext_vector_type(8)));
typedef __fp16   g2 __attribute__((ext_vector_type(2)));
typedef float    v4f __attribute__((ext_vector_type(4)));

namespace {
constexpr int BATCH = 4;
constexpr int IN_N  = 32;
constexpr int OUT_N = 32;
constexpr int H_IN  = 28;     // input spatial
constexpr int HW    = 26;     // output spatial (28-3+1)
constexpr int NI    = 288;    // IN_N * 3 * 3
constexpr int D     = 16;
constexpr int ITERS = 7;
// 1/(sqrt(16)*0.75) * log2(e): exp(x/3) == exp2(x * SCALE_L2E).
constexpr float SCALE_L2E = 0.48089834696298783f;
// Combine constant: 0.375 * ln2. Step 6 multiplies by sQtT = w*(log2e/3), so the
// total is np*3*ln2 * w*log2e/3 = np*w EXACTLY (ln2*log2e == 1). Do NOT rely on
// "uniform scale cancels in LayerNorm" -- it fails when var ~ EPS (measured r5/r6:
// absmax 0.43 from EPS-dominated rows amplifying the residual scale by ~1/sqrt(EPS)).
constexpr float COMB_C = 0.375f * 0.69314718055994531f;
constexpr float EPS = 1e-5f;

constexpr int VH_S = 16;      // sVh row stride (halves, 32 B); granule-XOR swizzled
constexpr int AT_S = 296;     // sAt row stride (halves, 592 B): 16B-aligned b128 rows
constexpr int P_S  = 36;      // step-5 partial stride (floats)

// DPP ctrl encodings
constexpr int DPP_XOR1 = 0xB1;   // quad_perm [1,0,3,2]
constexpr int DPP_XOR2 = 0x4E;   // quad_perm [2,3,0,1]
constexpr int DPP_ROR4 = 0x124;  // row rotate 4 (within 16)
constexpr int DPP_ROR8 = 0x128;  // row rotate 8 == xor8 within 16
}

union H8U { h2 q[4]; h8 v; int2 i2[2]; };

static __device__ __forceinline__ int h2bits(h2 x) { union { h2 h; int i; } u; u.h = x; return u.i; }

// cvt_pkrtz returns __fp16x2; bit-cast to our _Float16-based h2
static __device__ __forceinline__ h2 pkrtz(float a, float b) {
  union { g2 g; h2 h; } u;
  u.g = __builtin_amdgcn_cvt_pkrtz(a, b);
  return u.h;
}

static __device__ __forceinline__ float dot2f(h2 a, h2 b, float c) {
#if __has_builtin(__builtin_amdgcn_fdot2)
  return __builtin_amdgcn_fdot2(a, b, c, false);
#else
  return c + (float)a.x * (float)b.x + (float)a.y * (float)b.y;
#endif
}

static __device__ __forceinline__ float exp2_fast(float x) {
#if __has_builtin(__builtin_amdgcn_exp2f)
  return __builtin_amdgcn_exp2f(x);      // bare v_exp_f32 (computes 2^x)
#else
  return __expf(x * 0.6931471805599453f);
#endif
}

// x + dpp_perm(x): cross-lane add on the VALU pipe (no ds_bpermute)
template <int CTRL>
static __device__ __forceinline__ float dpp_add(float x) {
  union { float f; int i; } s, r;
  s.f = x;
  r.i = __builtin_amdgcn_update_dpp(s.i, s.i, CTRL, 0xF, 0xF, false);
  return x + r.f;
}

extern "C" __global__ __launch_bounds__(256, 4)
void capsule_fused(const float* __restrict__ input,
                   const float* __restrict__ w_current,
                   const float* __restrict__ w_next,
                   const float* __restrict__ ln_scale,
                   const float* __restrict__ ln_bias,
                   float* __restrict__ out) {
  // Manual LDS carving: 32512 B total.
  __shared__ __align__(16) unsigned char smem[32512];
  _Float16* sVh  = (_Float16*)(smem);            // [288][16] halves, granule-swizzled (9216 B)
  float*    Pf   = (float*)(smem);               // overlay: step-5 partials [4][16][36] (9216 B)
  _Float16* sAt  = (_Float16*)(smem + 9216);     // A^T [32][296] halves (18944 B)
  _Float16* sQtT = (_Float16*)(smem + 28160);    // fp16 w_next[o][d] * SCALE_L2E (1024 B)
  float*    sU   = (float*)(smem + 29184);       // fp32 finals: v[NI..NI+31] (1280 B region)
  float*    sScr = (float*)(smem + 30464);       // step3 scratch / np [16][32] (2048 B)
  // step-3 carving of sScr:
  float*    Pw   = sScr;                          // col-sum partials [4 waves][32 o] (512 B)
  _Float16* sUh  = (_Float16*)((unsigned char*)sScr + 512);   // u f16 [288] (576 B, 16B-aligned)
  _Float16* sVf  = (_Float16*)((unsigned char*)sScr + 1088);  // v f16 [32] (64 B, 16B-aligned)

  const int t   = threadIdx.x;
  const int l   = t & 63;
  const int wv  = t >> 6;
  const int bid = blockIdx.x;
  const int b   = bid / (HW * HW);
  const int sp  = bid % (HW * HW);
  const int hh  = sp / HW;
  const int ww  = sp % HW;

  H8U zu; zu.i2[0] = make_int2(0, 0); zu.i2[1] = make_int2(0, 0);
  const h8 zero8 = zu.v;

  // stage fp16 qf: sQtT[o][d] = fp16(w_next[o][d] * SCALE_L2E)   (256 h2 pairs, one pass)
  {
    const int o = t >> 3, dp = t & 7;
    const float a0 = w_next[o * 16 + 2 * dp]     * SCALE_L2E;
    const float a1 = w_next[o * 16 + 2 * dp + 1] * SCALE_L2E;
    *(h2*)(sQtT + o * 16 + 2 * dp) = pkrtz(a0, a1);
  }

  // ---- step 1: V[i][p*4+r] = sum_q pose[p][q]*w_current[q][r]; store f16 swizzled ----
  // swizzle: halves h of row i live at i*16 + 8*((h>>3) ^ ((i>>3)&1)) + (h&7)
  for (int i = t; i < NI; i += 256) {
    const int n = i / 9, kl = i % 9, ky = kl / 3, kx = kl % 3;
    const float* px = input + (((b * IN_N + n) * H_IN + (hh + ky)) * H_IN + (ww + kx)) * D;
    float p[16], wt[16];
    *(float4*)(p +  0) = *(const float4*)(px +  0);
    *(float4*)(p +  4) = *(const float4*)(px +  4);
    *(float4*)(p +  8) = *(const float4*)(px +  8);
    *(float4*)(p + 12) = *(const float4*)(px + 12);
    const float* wc = w_current + (kl * IN_N + n) * 16;
    *(float4*)(wt +  0) = *(const float4*)(wc +  0);
    *(float4*)(wt +  4) = *(const float4*)(wc +  4);
    *(float4*)(wt +  8) = *(const float4*)(wc +  8);
    *(float4*)(wt + 12) = *(const float4*)(wc + 12);
    float vv[16];
    #pragma unroll
    for (int pp = 0; pp < 4; ++pp)
      #pragma unroll
      for (int rr = 0; rr < 4; ++rr)
        vv[pp * 4 + rr] = p[pp*4+0]*wt[0+rr] + p[pp*4+1]*wt[4+rr]
                        + p[pp*4+2]*wt[8+rr] + p[pp*4+3]*wt[12+rr];
    H8U lo, hi;
    #pragma unroll
    for (int jj = 0; jj < 4; ++jj) {
      lo.q[jj] = pkrtz(vv[2*jj],     vv[2*jj + 1]);
      hi.q[jj] = pkrtz(vv[8 + 2*jj], vv[8 + 2*jj + 1]);
    }
    const int flip8 = ((i >> 3) & 1) * 8;
    *(h8*)(sVh + i * VH_S + flip8)       = lo.v;
    *(h8*)(sVh + i * VH_S + (flip8 ^ 8)) = hi.v;
  }
  __syncthreads();

  // ---- step 2: A^T[o][i] = exp2(Vf[i].qf_l2e[o]) via MFMA 16x16x32 (K zero-padded) ----
  {
    const int lo16 = l & 15;
    const int q4   = l >> 4;          // k-quad
    const int kq   = (q4 & 1) * 8;    // real k base for quads 0,1
    const bool hiK = (q4 >= 2);       // quads 2,3 = zero-pad region (k>=16)
    h8 bf[2];
    #pragma unroll
    for (int nt = 0; nt < 2; ++nt) {
      const int o = lo16 + 16 * nt;
      bf[nt] = hiK ? zero8 : *(const h8*)(sQtT + o * 16 + kq);   // halves kq..kq+7 of row o
    }
    const int vflip = 8 * ((q4 & 1) ^ ((lo16 >> 3) & 1));
    for (int mt = wv; mt < 18; mt += 4) {
      const int m = mt * 16 + lo16;
      h8 af = zero8;
      if (!hiK) af = *(const h8*)(sVh + m * VH_S + vflip);
      #pragma unroll
      for (int nt = 0; nt < 2; ++nt) {
        v4f acc = {0.f, 0.f, 0.f, 0.f};
        acc = __builtin_amdgcn_mfma_f32_16x16x32_f16(af, bf[nt], acc, 0, 0, 0);
        // D: col(o-within-tile)=l&15, row(i-offset)=4*q4+reg
        const int o  = lo16 + 16 * nt;
        const int ib = mt * 16 + 4 * q4;
        h2 p0 = pkrtz(exp2_fast(acc[0]), exp2_fast(acc[1]));
        h2 p1 = pkrtz(exp2_fast(acc[2]), exp2_fast(acc[3]));
        int2 wr; wr.x = h2bits(p0); wr.y = h2bits(p1);
        *(int2*)(sAt + o * AT_S + ib) = wr;   // A^T[o][ib..ib+3]
      }
    }
  }
  __syncthreads();

  // ---- step 3: Sinkhorn, minimum-VALU form, 2 barriers/iter.
  // u-pass: row-per-thread, 16 fdot2, no cross-lane. col-pass: A^T u on the MFMA pipe
  // with u broadcast into all 16 B-columns. v-finalize: ALL waves redundantly (each
  // lane handles o=l&31); every wave writes the full sVf itself, so the next u-pass
  // reads values its OWN wave wrote -> no third barrier. Cross-wave duplicate writes
  // are bit-identical (same Pw inputs, same rcp) -> benign WAW.
  // v rescaled: v = 8/colsum (exact compensation via COMB_C in the combine).
  {
    const int lo16 = l & 15;
    const int q4   = l >> 4;
    // preload A-row for row i=t (and i=t+32 for t>=224): strided u16 reads, one-time.
    // Arow[oo] = (A[i][2oo], A[i][2oo+1])
    h2 Arow[16];
    {
      const _Float16* colp = sAt + t;
      #pragma unroll
      for (int oo = 0; oo < 16; ++oo) {
        h2 a; a.x = colp[(2*oo) * AT_S]; a.y = colp[(2*oo + 1) * AT_S];
        Arow[oo] = a;
      }
    }
    h2 Arow2[16];
    if (t >= 224) {
      const _Float16* colp = sAt + (t + 32);
      #pragma unroll
      for (int oo = 0; oo < 16; ++oo) {
        h2 a; a.x = colp[(2*oo) * AT_S]; a.y = colp[(2*oo + 1) * AT_S];
        Arow2[oo] = a;
      }
    }

    for (int it = 0; it < ITERS; ++it) {
      // v fragments: v-pairs (v[2j],v[2j+1]); iter 0 = ones
      H8U va, vb, vc, vd;
      if (it == 0) {
        const h2 one2 = pkrtz(1.0f, 1.0f);
        #pragma unroll
        for (int jj = 0; jj < 4; ++jj) { va.q[jj] = one2; vb.q[jj] = one2; vc.q[jj] = one2; vd.q[jj] = one2; }
      } else {
        va.v = *(const h8*)(sVf);        // v[0..7]   (own-wave-written last iter)
        vb.v = *(const h8*)(sVf + 8);    // v[8..15]
        vc.v = *(const h8*)(sVf + 16);   // v[16..23]
        vd.v = *(const h8*)(sVf + 24);   // v[24..31]
      }
      // u-pass: row sums, fully in-lane (16 fdot2, fp32 accum)
      float s0 = 0.f, s1 = 0.f;
      #pragma unroll
      for (int oo = 0; oo < 4; ++oo) {
        s0 = dot2f(Arow[oo],      va.q[oo], s0);
        s0 = dot2f(Arow[4 + oo],  vb.q[oo], s0);
        s1 = dot2f(Arow[8 + oo],  vc.q[oo], s1);
        s1 = dot2f(Arow[12 + oo], vd.q[oo], s1);
      }
      const float u = __builtin_amdgcn_rcpf(s0 + s1);
      sUh[t] = (_Float16)u;
      if (t >= 224) {
        float e0 = 0.f, e1 = 0.f;
        #pragma unroll
        for (int oo = 0; oo < 4; ++oo) {
          e0 = dot2f(Arow2[oo],      va.q[oo], e0);
          e0 = dot2f(Arow2[4 + oo],  vb.q[oo], e0);
          e1 = dot2f(Arow2[8 + oo],  vc.q[oo], e1);
          e1 = dot2f(Arow2[12 + oo], vd.q[oo], e1);
        }
        const float u2 = __builtin_amdgcn_rcpf(e0 + e1);
        sUh[t + 32] = (_Float16)u2;
      }
      __syncthreads();   // BAR A: sUh complete

      // col-pass: acc[o] = sum_k A^T[o][k] u[k] on MFMA; waves split the 9 k-steps
      v4f acc0 = {0.f, 0.f, 0.f, 0.f};
      v4f acc1 = {0.f, 0.f, 0.f, 0.f};
      for (int ks = wv; ks < 9; ks += 4) {
        const int kb = ks * 32 + q4 * 8;
        const h8 uf  = *(const h8*)(sUh + kb);                 // B[k][n]=u[k] for all n (broadcast)
        const h8 af0 = *(const h8*)(sAt + lo16 * AT_S + kb);
        const h8 af1 = *(const h8*)(sAt + (16 + lo16) * AT_S + kb);
        acc0 = __builtin_amdgcn_mfma_f32_16x16x32_f16(af0, uf, acc0, 0, 0, 0);
        acc1 = __builtin_amdgcn_mfma_f32_16x16x32_f16(af1, uf, acc1, 0, 0, 0);
      }
      // D cols all equal; rows o = tile*16 + 4*q4 + reg. One lane-group writes.
      if (lo16 == 0) {
        *(v4f*)(Pw + wv * 32 + 0  + 4 * q4) = acc0;
        *(v4f*)(Pw + wv * 32 + 16 + 4 * q4) = acc1;
      }
      __syncthreads();   // BAR B: Pw complete (also: all sUh reads done)

      // v-finalize, ALL lanes (o covered twice per wave; dup writes identical)
      {
        const int o = l & 31;
        const float S = Pw[0 * 32 + o] + Pw[1 * 32 + o] + Pw[2 * 32 + o] + Pw[3 * 32 + o];
        const float v = 8.0f * __builtin_amdgcn_rcpf(S);
        sVf[o] = (_Float16)v;
        if (it == ITERS - 1 && t < 32) sU[NI + o] = v;   // fp32 final v for the combine
      }
      // no BAR C: next u-pass reads sVf this wave just wrote (lgkmcnt orders it)
    }
  }

  // ---- step 5: np~[o][d] = sum_k (A^T[o][k]*u_k) * V[k][d] via MFMA 16x16x32 ----
  // u folded into the A-operand with v_pk_mul_f16 (u from sUh, final-iter f16 values);
  // B-fragment is raw f16 pair-assembly from sVh (zero VALU beyond the pack).
  // (sUh final writes were pre-BAR-A of last iter; BAR B orders them vs these reads.)
  v4f acc5_0 = {0.f, 0.f, 0.f, 0.f};
  v4f acc5_1 = {0.f, 0.f, 0.f, 0.f};
  {
    const int d  = l & 15;
    const int q4 = l >> 4;
    // swizzled half offset for column d of row r: 8*((d>>3) ^ ((r>>3)&1)) + (d&7);
    // (r>>3)&1 == q4&1 for all rows r = kt*32 + q4*8 + z (z<8) -> per-lane constant
    const int doff = 8 * ((d >> 3) ^ (q4 & 1)) + (d & 7);
    for (int kt = wv; kt < 9; kt += 4) {
      const int kg = kt * 32 + q4 * 8;
      H8U uu; uu.v = *(const h8*)(sUh + kg);                 // u[kg..kg+7] f16 (broadcast)
      H8U a0; a0.v = *(const h8*)(sAt + d * AT_S        + kg);
      H8U a1; a1.v = *(const h8*)(sAt + (16 + d) * AT_S + kg);
      H8U a0u, a1u;
      #pragma unroll
      for (int jj = 0; jj < 4; ++jj) {
        a0u.q[jj] = a0.q[jj] * uu.q[jj];                     // v_pk_mul_f16
        a1u.q[jj] = a1.q[jj] * uu.q[jj];
      }
      H8U bu;
      #pragma unroll
      for (int jj = 0; jj < 4; ++jj) {
        h2 bq;
        bq.x = sVh[(kg + 2*jj)     * VH_S + doff];
        bq.y = sVh[(kg + 2*jj + 1) * VH_S + doff];
        bu.q[jj] = bq;
      }
      acc5_0 = __builtin_amdgcn_mfma_f32_16x16x32_f16(a0u.v, bu.v, acc5_0, 0, 0, 0);
      acc5_1 = __builtin_amdgcn_mfma_f32_16x16x32_f16(a1u.v, bu.v, acc5_1, 0, 0, 0);
    }
  }
  __syncthreads();   // all sVh/sAt/sUh reads done -> safe to overlay P into sVh
  {
    const int d = l & 15, q4 = l >> 4;
    // D: col=d, row(o-offset)=4*q4+reg
    *(v4f*)(Pf + (wv * 16 + d) * P_S + 0  + 4 * q4) = acc5_0;
    *(v4f*)(Pf + (wv * 16 + d) * P_S + 16 + 4 * q4) = acc5_1;
  }
  __syncthreads();
  // combine K-partials: sScr = np*3*ln2 = S~ * v~_o * (3/8)*ln2.
  // (the /8 undoes the v rescale; ln2 cancels sQtT's log2e in step 6 EXACTLY)
  #pragma unroll
  for (int pass = 0; pass < 2; ++pass) {
    const int e = t + 256 * pass;
    const int o = e & 31, dd = e >> 5;
    const float S = Pf[(0 * 16 + dd) * P_S + o] + Pf[(1 * 16 + dd) * P_S + o]
                  + Pf[(2 * 16 + dd) * P_S + o] + Pf[(3 * 16 + dd) * P_S + o];
    sScr[dd * 32 + o] = S * COMB_C * sU[NI + o];
  }
  __syncthreads();

  // ---- step 6: out[o][p*4+r] = sum_q np[o][p*4+q]*w_next[o][q*4+r]; LayerNorm over d ----
  // np*3*ln2 times w_next*(log2e/3) == np*w_next exactly -> EPS-consistent LN.
  {
    float vals[2];
    #pragma unroll
    for (int h2p = 0; h2p < 2; ++h2p) {
      const int e = t + h2p * 256;
      const int o = e >> 4, dd = e & 15;
      const int pp = dd >> 2, rr = dd & 3;
      float acc = 0.f;
      #pragma unroll
      for (int q = 0; q < 4; ++q)
        acc += sScr[(pp * 4 + q) * 32 + o] * (float)sQtT[o * 16 + q * 4 + rr];
      vals[h2p] = acc;
    }
    // LN over the 16 d's: full-16 DPP reduction (quad sums, then rotate-4/8)
    float s0 = vals[0], q0 = vals[0] * vals[0];
    float s1 = vals[1], q1 = vals[1] * vals[1];
    s0 = dpp_add<DPP_XOR1>(s0); q0 = dpp_add<DPP_XOR1>(q0);
    s1 = dpp_add<DPP_XOR1>(s1); q1 = dpp_add<DPP_XOR1>(q1);
    s0 = dpp_add<DPP_XOR2>(s0); q0 = dpp_add<DPP_XOR2>(q0);
    s1 = dpp_add<DPP_XOR2>(s1); q1 = dpp_add<DPP_XOR2>(q1);
    s0 = dpp_add<DPP_ROR4>(s0); q0 = dpp_add<DPP_ROR4>(q0);
    s1 = dpp_add<DPP_ROR4>(s1); q1 = dpp_add<DPP_ROR4>(q1);
    s0 = dpp_add<DPP_ROR8>(s0); q0 = dpp_add<DPP_ROR8>(q0);
    s1 = dpp_add<DPP_ROR8>(s1); q1 = dpp_add<DPP_ROR8>(q1);
    #pragma unroll
    for (int h2p = 0; h2p < 2; ++h2p) {
      const int e = t + h2p * 256;
      const int o = e >> 4, dd = e & 15;
      const float ss = h2p ? s1 : s0;
      const float qq = h2p ? q1 : q0;
      const float mu   = ss * (1.0f / 16.0f);
      const float var  = qq * (1.0f / 16.0f) - mu * mu;
      const float rstd = rsqrtf(var + EPS);
      const float y = (vals[h2p] - mu) * rstd * ln_scale[dd] + ln_bias[dd];
      out[(((b * OUT_N + o) * HW + hh) * HW + ww) * D + dd] = y;
    }
  }
}

extern "C" void kernel_launch(void* const* d_in, const int* in_sizes, int n_in,
                              void* d_out, int out_size, void* d_ws, size_t ws_size,
                              hipStream_t stream) {
  const float* input     = (const float*)d_in[0];
  const float* w_current = (const float*)d_in[1];
  const float* w_next    = (const float*)d_in[2];
  const float* ln_scale  = (const float*)d_in[3];
  const float* ln_bias   = (const float*)d_in[4];
  float* outp = (float*)d_out;

  dim3 grid(BATCH * HW * HW);   // 2704 blocks, one per (b, h, w)
  dim3 block(256);
  capsule_fused<<<grid, block, 0, stream>>>(input, w_current, w_next,
                                            ln_scale, ln_bias, outp);
}

// Round 10
// 95.408 us; speedup vs baseline: 1.1431x; 1.0148x over previous
//
#include <hip/hip_runtime.h>

typedef _Float16 h2 __attribute__((ext_vector_type(2)));
typedef _Float16 h8 __attribute__((ext_vector_type(8)));
typedef __fp16   g2 __attribute__((ext_vector_type(2)));
typedef float    v4f __attribute__((ext_vector_type(4)));

namespace {
constexpr int BATCH = 4;
constexpr int IN_N  = 32;
constexpr int OUT_N = 32;
constexpr int H_IN  = 28;     // input spatial
constexpr int HW    = 26;     // output spatial (28-3+1)
constexpr int NI    = 288;    // IN_N * 3 * 3
constexpr int D     = 16;
constexpr int ITERS = 7;
// 1/(sqrt(16)*0.75) * log2(e): exp(x/3) == exp2(x * SCALE_L2E).
constexpr float SCALE_L2E = 0.48089834696298783f;
// Combine constant: 0.375 * ln2. Step 6 multiplies by sQtT = w*(log2e/3), so the
// total is np*3*ln2 * w*log2e/3 = np*w EXACTLY (ln2*log2e == 1). Do NOT rely on
// "uniform scale cancels in LayerNorm" -- it fails when var ~ EPS (measured r5/r6:
// absmax 0.43 from EPS-dominated rows amplifying the residual scale by ~1/sqrt(EPS)).
constexpr float COMB_C = 0.375f * 0.69314718055994531f;
constexpr float EPS = 1e-5f;

constexpr int VH_S = 16;      // sVh row stride (halves, 32 B); granule-XOR swizzled
constexpr int AT_S = 296;     // sAt row stride (halves, 592 B): 16B-aligned b128 rows
constexpr int P_S  = 36;      // step-5 partial stride (floats)

// DPP ctrl encodings
constexpr int DPP_XOR1 = 0xB1;   // quad_perm [1,0,3,2]
constexpr int DPP_XOR2 = 0x4E;   // quad_perm [2,3,0,1]
constexpr int DPP_ROR4 = 0x124;  // row rotate 4 (within 16)
constexpr int DPP_ROR8 = 0x128;  // row rotate 8 == xor8 within 16
}

union H8U { h2 q[4]; h8 v; int2 i2[2]; };

static __device__ __forceinline__ int h2bits(h2 x) { union { h2 h; int i; } u; u.h = x; return u.i; }

// cvt_pkrtz returns __fp16x2; bit-cast to our _Float16-based h2
static __device__ __forceinline__ h2 pkrtz(float a, float b) {
  union { g2 g; h2 h; } u;
  u.g = __builtin_amdgcn_cvt_pkrtz(a, b);
  return u.h;
}

static __device__ __forceinline__ float dot2f(h2 a, h2 b, float c) {
#if __has_builtin(__builtin_amdgcn_fdot2)
  return __builtin_amdgcn_fdot2(a, b, c, false);
#else
  return c + (float)a.x * (float)b.x + (float)a.y * (float)b.y;
#endif
}

static __device__ __forceinline__ float exp2_fast(float x) {
#if __has_builtin(__builtin_amdgcn_exp2f)
  return __builtin_amdgcn_exp2f(x);      // bare v_exp_f32 (computes 2^x)
#else
  return __expf(x * 0.6931471805599453f);
#endif
}

// x + dpp_perm(x): cross-lane add on the VALU pipe (no ds_bpermute)
template <int CTRL>
static __device__ __forceinline__ float dpp_add(float x) {
  union { float f; int i; } s, r;
  s.f = x;
  r.i = __builtin_amdgcn_update_dpp(s.i, s.i, CTRL, 0xF, 0xF, false);
  return x + r.f;
}

extern "C" __global__ __launch_bounds__(256, 5)
void capsule_fused(const float* __restrict__ input,
                   const float* __restrict__ w_current,
                   const float* __restrict__ w_next,
                   const float* __restrict__ ln_scale,
                   const float* __restrict__ ln_bias,
                   float* __restrict__ out) {
  // Manual LDS carving: 31360 B total -> rounds to 31744 -> 5 blocks/CU
  // (5 x 31744 = 158720 <= 160 KiB with ~5 KiB headroom for runtime reserve).
  // R2's 5-block attempt used 32768x5 = exactly 160 KiB -> silently fell to 4.
  __shared__ __align__(16) unsigned char smem[31360];
  _Float16* sVh  = (_Float16*)(smem);            // [288][16] halves, granule-swizzled (9216 B)
  float*    Pf   = (float*)(smem);               // overlay: step-5 partials [4][16][36] (9216 B)
  _Float16* sAt  = (_Float16*)(smem + 9216);     // A^T [32][296] halves (18944 B)
  _Float16* sQtT = (_Float16*)(smem + 28160);    // fp16 w_next[o][d] * SCALE_L2E (1024 B)
  float*    sUv  = (float*)(smem + 29184);       // fp32 final v [32] (128 B)
  float*    sScr = (float*)(smem + 29312);       // step3 scratch / np [16][32] (2048 B)
  // step-3 carving of sScr:
  float*    Pw   = sScr;                          // col-sum partials [4 waves][32 o] (512 B)
  _Float16* sUh  = (_Float16*)((unsigned char*)sScr + 512);   // u f16 [288] (576 B, 16B-aligned)
  _Float16* sVf  = (_Float16*)((unsigned char*)sScr + 1088);  // v f16 [32] (64 B, 16B-aligned)

  const int t   = threadIdx.x;
  const int l   = t & 63;
  const int wv  = t >> 6;
  const int bid = blockIdx.x;
  const int b   = bid / (HW * HW);
  const int sp  = bid % (HW * HW);
  const int hh  = sp / HW;
  const int ww  = sp % HW;

  H8U zu; zu.i2[0] = make_int2(0, 0); zu.i2[1] = make_int2(0, 0);
  const h8 zero8 = zu.v;

  // stage fp16 qf: sQtT[o][d] = fp16(w_next[o][d] * SCALE_L2E)   (256 h2 pairs, one pass)
  {
    const int o = t >> 3, dp = t & 7;
    const float a0 = w_next[o * 16 + 2 * dp]     * SCALE_L2E;
    const float a1 = w_next[o * 16 + 2 * dp + 1] * SCALE_L2E;
    *(h2*)(sQtT + o * 16 + 2 * dp) = pkrtz(a0, a1);
  }

  // ---- step 1: V[i][p*4+r] = sum_q pose[p][q]*w_current[q][r]; store f16 swizzled ----
  // swizzle: halves h of row i live at i*16 + 8*((h>>3) ^ ((i>>3)&1)) + (h&7)
  for (int i = t; i < NI; i += 256) {
    const int n = i / 9, kl = i % 9, ky = kl / 3, kx = kl % 3;
    const float* px = input + (((b * IN_N + n) * H_IN + (hh + ky)) * H_IN + (ww + kx)) * D;
    float p[16], wt[16];
    *(float4*)(p +  0) = *(const float4*)(px +  0);
    *(float4*)(p +  4) = *(const float4*)(px +  4);
    *(float4*)(p +  8) = *(const float4*)(px +  8);
    *(float4*)(p + 12) = *(const float4*)(px + 12);
    const float* wc = w_current + (kl * IN_N + n) * 16;
    *(float4*)(wt +  0) = *(const float4*)(wc +  0);
    *(float4*)(wt +  4) = *(const float4*)(wc +  4);
    *(float4*)(wt +  8) = *(const float4*)(wc +  8);
    *(float4*)(wt + 12) = *(const float4*)(wc + 12);
    float vv[16];
    #pragma unroll
    for (int pp = 0; pp < 4; ++pp)
      #pragma unroll
      for (int rr = 0; rr < 4; ++rr)
        vv[pp * 4 + rr] = p[pp*4+0]*wt[0+rr] + p[pp*4+1]*wt[4+rr]
                        + p[pp*4+2]*wt[8+rr] + p[pp*4+3]*wt[12+rr];
    H8U lo, hi;
    #pragma unroll
    for (int jj = 0; jj < 4; ++jj) {
      lo.q[jj] = pkrtz(vv[2*jj],     vv[2*jj + 1]);
      hi.q[jj] = pkrtz(vv[8 + 2*jj], vv[8 + 2*jj + 1]);
    }
    const int flip8 = ((i >> 3) & 1) * 8;
    *(h8*)(sVh + i * VH_S + flip8)       = lo.v;
    *(h8*)(sVh + i * VH_S + (flip8 ^ 8)) = hi.v;
  }
  __syncthreads();

  // ---- step 2: A^T[o][i] = exp2(Vf[i].qf_l2e[o]) via MFMA 16x16x32 (K zero-padded) ----
  {
    const int lo16 = l & 15;
    const int q4   = l >> 4;          // k-quad
    const int kq   = (q4 & 1) * 8;    // real k base for quads 0,1
    const bool hiK = (q4 >= 2);       // quads 2,3 = zero-pad region (k>=16)
    h8 bf[2];
    #pragma unroll
    for (int nt = 0; nt < 2; ++nt) {
      const int o = lo16 + 16 * nt;
      bf[nt] = hiK ? zero8 : *(const h8*)(sQtT + o * 16 + kq);   // halves kq..kq+7 of row o
    }
    const int vflip = 8 * ((q4 & 1) ^ ((lo16 >> 3) & 1));
    for (int mt = wv; mt < 18; mt += 4) {
      const int m = mt * 16 + lo16;
      h8 af = zero8;
      if (!hiK) af = *(const h8*)(sVh + m * VH_S + vflip);
      #pragma unroll
      for (int nt = 0; nt < 2; ++nt) {
        v4f acc = {0.f, 0.f, 0.f, 0.f};
        acc = __builtin_amdgcn_mfma_f32_16x16x32_f16(af, bf[nt], acc, 0, 0, 0);
        // D: col(o-within-tile)=l&15, row(i-offset)=4*q4+reg
        const int o  = lo16 + 16 * nt;
        const int ib = mt * 16 + 4 * q4;
        h2 p0 = pkrtz(exp2_fast(acc[0]), exp2_fast(acc[1]));
        h2 p1 = pkrtz(exp2_fast(acc[2]), exp2_fast(acc[3]));
        int2 wr; wr.x = h2bits(p0); wr.y = h2bits(p1);
        *(int2*)(sAt + o * AT_S + ib) = wr;   // A^T[o][ib..ib+3]
      }
    }
  }
  __syncthreads();

  // ---- step 3: Sinkhorn, minimum-VALU form, 2 barriers/iter.
  // u-pass: row-per-thread, 16 fdot2, no cross-lane. col-pass: A^T u on the MFMA pipe
  // with u broadcast into all 16 B-columns. v-finalize: ALL waves redundantly (each
  // lane handles o=l&31); every wave writes the full sVf itself, so the next u-pass
  // reads values its OWN wave wrote -> no third barrier. Cross-wave duplicate writes
  // are bit-identical (same Pw inputs, same rcp) -> benign WAW.
  // v rescaled: v = 8/colsum (exact compensation via COMB_C in the combine).
  {
    const int lo16 = l & 15;
    const int q4   = l >> 4;
    // preload A-row for row i=t (and i=t+32 for t>=224): strided u16 reads, one-time.
    // Arow[oo] = (A[i][2oo], A[i][2oo+1])
    h2 Arow[16];
    {
      const _Float16* colp = sAt + t;
      #pragma unroll
      for (int oo = 0; oo < 16; ++oo) {
        h2 a; a.x = colp[(2*oo) * AT_S]; a.y = colp[(2*oo + 1) * AT_S];
        Arow[oo] = a;
      }
    }
    h2 Arow2[16];
    if (t >= 224) {
      const _Float16* colp = sAt + (t + 32);
      #pragma unroll
      for (int oo = 0; oo < 16; ++oo) {
        h2 a; a.x = colp[(2*oo) * AT_S]; a.y = colp[(2*oo + 1) * AT_S];
        Arow2[oo] = a;
      }
    }

    for (int it = 0; it < ITERS; ++it) {
      // v fragments: v-pairs (v[2j],v[2j+1]); iter 0 = ones
      H8U va, vb, vc, vd;
      if (it == 0) {
        const h2 one2 = pkrtz(1.0f, 1.0f);
        #pragma unroll
        for (int jj = 0; jj < 4; ++jj) { va.q[jj] = one2; vb.q[jj] = one2; vc.q[jj] = one2; vd.q[jj] = one2; }
      } else {
        va.v = *(const h8*)(sVf);        // v[0..7]   (own-wave-written last iter)
        vb.v = *(const h8*)(sVf + 8);    // v[8..15]
        vc.v = *(const h8*)(sVf + 16);   // v[16..23]
        vd.v = *(const h8*)(sVf + 24);   // v[24..31]
      }
      // u-pass: row sums, fully in-lane (16 fdot2, fp32 accum)
      float s0 = 0.f, s1 = 0.f;
      #pragma unroll
      for (int oo = 0; oo < 4; ++oo) {
        s0 = dot2f(Arow[oo],      va.q[oo], s0);
        s0 = dot2f(Arow[4 + oo],  vb.q[oo], s0);
        s1 = dot2f(Arow[8 + oo],  vc.q[oo], s1);
        s1 = dot2f(Arow[12 + oo], vd.q[oo], s1);
      }
      const float u = __builtin_amdgcn_rcpf(s0 + s1);
      sUh[t] = (_Float16)u;
      if (t >= 224) {
        float e0 = 0.f, e1 = 0.f;
        #pragma unroll
        for (int oo = 0; oo < 4; ++oo) {
          e0 = dot2f(Arow2[oo],      va.q[oo], e0);
          e0 = dot2f(Arow2[4 + oo],  vb.q[oo], e0);
          e1 = dot2f(Arow2[8 + oo],  vc.q[oo], e1);
          e1 = dot2f(Arow2[12 + oo], vd.q[oo], e1);
        }
        const float u2 = __builtin_amdgcn_rcpf(e0 + e1);
        sUh[t + 32] = (_Float16)u2;
      }
      __syncthreads();   // BAR A: sUh complete

      // col-pass: acc[o] = sum_k A^T[o][k] u[k] on MFMA; waves split the 9 k-steps
      v4f acc0 = {0.f, 0.f, 0.f, 0.f};
      v4f acc1 = {0.f, 0.f, 0.f, 0.f};
      for (int ks = wv; ks < 9; ks += 4) {
        const int kb = ks * 32 + q4 * 8;
        const h8 uf  = *(const h8*)(sUh + kb);                 // B[k][n]=u[k] for all n (broadcast)
        const h8 af0 = *(const h8*)(sAt + lo16 * AT_S + kb);
        const h8 af1 = *(const h8*)(sAt + (16 + lo16) * AT_S + kb);
        acc0 = __builtin_amdgcn_mfma_f32_16x16x32_f16(af0, uf, acc0, 0, 0, 0);
        acc1 = __builtin_amdgcn_mfma_f32_16x16x32_f16(af1, uf, acc1, 0, 0, 0);
      }
      // D cols all equal; rows o = tile*16 + 4*q4 + reg. One lane-group writes.
      if (lo16 == 0) {
        *(v4f*)(Pw + wv * 32 + 0  + 4 * q4) = acc0;
        *(v4f*)(Pw + wv * 32 + 16 + 4 * q4) = acc1;
      }
      __syncthreads();   // BAR B: Pw complete (also: all sUh reads done)

      // v-finalize, ALL lanes (o covered twice per wave; dup writes identical)
      {
        const int o = l & 31;
        const float S = Pw[0 * 32 + o] + Pw[1 * 32 + o] + Pw[2 * 32 + o] + Pw[3 * 32 + o];
        const float v = 8.0f * __builtin_amdgcn_rcpf(S);
        sVf[o] = (_Float16)v;
        if (it == ITERS - 1 && t < 32) sUv[o] = v;   // fp32 final v for the combine
      }
      // no BAR C: next u-pass reads sVf this wave just wrote (lgkmcnt orders it)
    }
  }

  // ---- step 5: np~[o][d] = sum_k (A^T[o][k]*u_k) * V[k][d] via MFMA 16x16x32 ----
  // u folded into the A-operand with v_pk_mul_f16 (u from sUh, final-iter f16 values);
  // B-fragment is raw f16 pair-assembly from sVh (zero VALU beyond the pack).
  // (sUh final writes were pre-BAR-A of last iter; BAR B orders them vs these reads.)
  v4f acc5_0 = {0.f, 0.f, 0.f, 0.f};
  v4f acc5_1 = {0.f, 0.f, 0.f, 0.f};
  {
    const int d  = l & 15;
    const int q4 = l >> 4;
    // swizzled half offset for column d of row r: 8*((d>>3) ^ ((r>>3)&1)) + (d&7);
    // (r>>3)&1 == q4&1 for all rows r = kt*32 + q4*8 + z (z<8) -> per-lane constant
    const int doff = 8 * ((d >> 3) ^ (q4 & 1)) + (d & 7);
    for (int kt = wv; kt < 9; kt += 4) {
      const int kg = kt * 32 + q4 * 8;
      H8U uu; uu.v = *(const h8*)(sUh + kg);                 // u[kg..kg+7] f16 (broadcast)
      H8U a0; a0.v = *(const h8*)(sAt + d * AT_S        + kg);
      H8U a1; a1.v = *(const h8*)(sAt + (16 + d) * AT_S + kg);
      H8U a0u, a1u;
      #pragma unroll
      for (int jj = 0; jj < 4; ++jj) {
        a0u.q[jj] = a0.q[jj] * uu.q[jj];                     // v_pk_mul_f16
        a1u.q[jj] = a1.q[jj] * uu.q[jj];
      }
      H8U bu;
      #pragma unroll
      for (int jj = 0; jj < 4; ++jj) {
        h2 bq;
        bq.x = sVh[(kg + 2*jj)     * VH_S + doff];
        bq.y = sVh[(kg + 2*jj + 1) * VH_S + doff];
        bu.q[jj] = bq;
      }
      acc5_0 = __builtin_amdgcn_mfma_f32_16x16x32_f16(a0u.v, bu.v, acc5_0, 0, 0, 0);
      acc5_1 = __builtin_amdgcn_mfma_f32_16x16x32_f16(a1u.v, bu.v, acc5_1, 0, 0, 0);
    }
  }
  __syncthreads();   // all sVh/sAt/sUh reads done -> safe to overlay P into sVh
  {
    const int d = l & 15, q4 = l >> 4;
    // D: col=d, row(o-offset)=4*q4+reg
    *(v4f*)(Pf + (wv * 16 + d) * P_S + 0  + 4 * q4) = acc5_0;
    *(v4f*)(Pf + (wv * 16 + d) * P_S + 16 + 4 * q4) = acc5_1;
  }
  __syncthreads();
  // combine K-partials: sScr = np*3*ln2 = S~ * v~_o * (3/8)*ln2.
  // (the /8 undoes the v rescale; ln2 cancels sQtT's log2e in step 6 EXACTLY)
  #pragma unroll
  for (int pass = 0; pass < 2; ++pass) {
    const int e = t + 256 * pass;
    const int o = e & 31, dd = e >> 5;
    const float S = Pf[(0 * 16 + dd) * P_S + o] + Pf[(1 * 16 + dd) * P_S + o]
                  + Pf[(2 * 16 + dd) * P_S + o] + Pf[(3 * 16 + dd) * P_S + o];
    sScr[dd * 32 + o] = S * COMB_C * sUv[o];
  }
  __syncthreads();

  // ---- step 6: out[o][p*4+r] = sum_q np[o][p*4+q]*w_next[o][q*4+r]; LayerNorm over d ----
  // np*3*ln2 times w_next*(log2e/3) == np*w_next exactly -> EPS-consistent LN.
  {
    float vals[2];
    #pragma unroll
    for (int h2p = 0; h2p < 2; ++h2p) {
      const int e = t + h2p * 256;
      const int o = e >> 4, dd = e & 15;
      const int pp = dd >> 2, rr = dd & 3;
      float acc = 0.f;
      #pragma unroll
      for (int q = 0; q < 4; ++q)
        acc += sScr[(pp * 4 + q) * 32 + o] * (float)sQtT[o * 16 + q * 4 + rr];
      vals[h2p] = acc;
    }
    // LN over the 16 d's: full-16 DPP reduction (quad sums, then rotate-4/8)
    float s0 = vals[0], q0 = vals[0] * vals[0];
    float s1 = vals[1], q1 = vals[1] * vals[1];
    s0 = dpp_add<DPP_XOR1>(s0); q0 = dpp_add<DPP_XOR1>(q0);
    s1 = dpp_add<DPP_XOR1>(s1); q1 = dpp_add<DPP_XOR1>(q1);
    s0 = dpp_add<DPP_XOR2>(s0); q0 = dpp_add<DPP_XOR2>(q0);
    s1 = dpp_add<DPP_XOR2>(s1); q1 = dpp_add<DPP_XOR2>(q1);
    s0 = dpp_add<DPP_ROR4>(s0); q0 = dpp_add<DPP_ROR4>(q0);
    s1 = dpp_add<DPP_ROR4>(s1); q1 = dpp_add<DPP_ROR4>(q1);
    s0 = dpp_add<DPP_ROR8>(s0); q0 = dpp_add<DPP_ROR8>(q0);
    s1 = dpp_add<DPP_ROR8>(s1); q1 = dpp_add<DPP_ROR8>(q1);
    #pragma unroll
    for (int h2p = 0; h2p < 2; ++h2p) {
      const int e = t + h2p * 256;
      const int o = e >> 4, dd = e & 15;
      const float ss = h2p ? s1 : s0;
      const float qq = h2p ? q1 : q0;
      const float mu   = ss * (1.0f / 16.0f);
      const float var  = qq * (1.0f / 16.0f) - mu * mu;
      const float rstd = rsqrtf(var + EPS);
      const float y = (vals[h2p] - mu) * rstd * ln_scale[dd] + ln_bias[dd];
      out[(((b * OUT_N + o) * HW + hh) * HW + ww) * D + dd] = y;
    }
  }
}

extern "C" void kernel_launch(void* const* d_in, const int* in_sizes, int n_in,
                              void* d_out, int out_size, void* d_ws, size_t ws_size,
                              hipStream_t stream) {
  const float* input     = (const float*)d_in[0];
  const float* w_current = (const float*)d_in[1];
  const float* w_next    = (const float*)d_in[2];
  const float* ln_scale  = (const float*)d_in[3];
  const float* ln_bias   = (const float*)d_in[4];
  float* outp = (float*)d_out;

  dim3 grid(BATCH * HW * HW);   // 2704 blocks, one per (b, h, w)
  dim3 block(256);
  capsule_fused<<<grid, block, 0, stream>>>(input, w_current, w_next,
                                            ln_scale, ln_bias, outp);
}

// Round 11
// 91.847 us; speedup vs baseline: 1.1874x; 1.0388x over previous
//
#include <hip/hip_runtime.h>

typedef _Float16 h2 __attribute__((ext_vector_type(2)));
typedef _Float16 h8 __attribute__((ext_vector_type(8)));
typedef __fp16   g2 __attribute__((ext_vector_type(2)));
typedef float    v4f __attribute__((ext_vector_type(4)));

namespace {
constexpr int BATCH = 4;
constexpr int IN_N  = 32;
constexpr int OUT_N = 32;
constexpr int H_IN  = 28;     // input spatial
constexpr int HW    = 26;     // output spatial (28-3+1)
constexpr int NI    = 288;    // IN_N * 3 * 3
constexpr int D     = 16;
constexpr int ITERS = 7;
// 1/(sqrt(16)*0.75) * log2(e): exp(x/3) == exp2(x * SCALE_L2E).
constexpr float SCALE_L2E = 0.48089834696298783f;
// Combine constant: 0.375 * ln2. Step 6 multiplies by sQtT = w*(log2e/3), so the
// total is np*3*ln2 * w*log2e/3 = np*w EXACTLY (ln2*log2e == 1). Do NOT rely on
// "uniform scale cancels in LayerNorm" -- it fails when var ~ EPS (measured r5/r6).
constexpr float COMB_C = 0.375f * 0.69314718055994531f;
constexpr float EPS = 1e-5f;

constexpr int VH_S = 16;      // sVh row stride (halves, 32 B); granule-XOR swizzled
constexpr int AT_S = 296;     // sAt row stride (halves, 592 B): 16B-aligned b128 rows
constexpr int P_S  = 36;      // step-5 partial stride (floats)

// DPP ctrl encodings
constexpr int DPP_XOR1 = 0xB1;   // quad_perm [1,0,3,2]
constexpr int DPP_XOR2 = 0x4E;   // quad_perm [2,3,0,1]
constexpr int DPP_ROR4 = 0x124;  // row rotate 4 (within 16)
constexpr int DPP_ROR8 = 0x128;  // row rotate 8 == xor8 within 16
}

union H8U { h2 q[4]; h8 v; int2 i2[2]; };

static __device__ __forceinline__ int h2bits(h2 x) { union { h2 h; int i; } u; u.h = x; return u.i; }

// cvt_pkrtz returns __fp16x2; bit-cast to our _Float16-based h2
static __device__ __forceinline__ h2 pkrtz(float a, float b) {
  union { g2 g; h2 h; } u;
  u.g = __builtin_amdgcn_cvt_pkrtz(a, b);
  return u.h;
}

static __device__ __forceinline__ float dot2f(h2 a, h2 b, float c) {
#if __has_builtin(__builtin_amdgcn_fdot2)
  return __builtin_amdgcn_fdot2(a, b, c, false);
#else
  return c + (float)a.x * (float)b.x + (float)a.y * (float)b.y;
#endif
}

static __device__ __forceinline__ float exp2_fast(float x) {
#if __has_builtin(__builtin_amdgcn_exp2f)
  return __builtin_amdgcn_exp2f(x);      // bare v_exp_f32 (computes 2^x)
#else
  return __expf(x * 0.6931471805599453f);
#endif
}

// x + dpp_perm(x): cross-lane add on the VALU pipe (no ds_bpermute)
template <int CTRL>
static __device__ __forceinline__ float dpp_add(float x) {
  union { float f; int i; } s, r;
  s.f = x;
  r.i = __builtin_amdgcn_update_dpp(s.i, s.i, CTRL, 0xF, 0xF, false);
  return x + r.f;
}

extern "C" __global__ __launch_bounds__(256, 5)
void capsule_fused(const float* __restrict__ input,
                   const float* __restrict__ w_current,
                   const float* __restrict__ w_next,
                   const float* __restrict__ ln_scale,
                   const float* __restrict__ ln_bias,
                   float* __restrict__ out) {
  // Manual LDS carving: 31360 B -> 5 blocks/CU capacity.
  __shared__ __align__(16) unsigned char smem[31360];
  _Float16* sVh  = (_Float16*)(smem);            // [288][16] halves, granule-swizzled (9216 B)
  float*    Pf   = (float*)(smem);               // overlay: step-5 partials [4][16][36] (9216 B)
  _Float16* sAt  = (_Float16*)(smem + 9216);     // A^T [32][296] halves (18944 B)
  _Float16* sQtT = (_Float16*)(smem + 28160);    // fp16 w_next[o][d] * SCALE_L2E (1024 B)
  float*    sUv  = (float*)(smem + 29184);       // fp32 final v [32] (128 B)
  float*    sScr = (float*)(smem + 29312);       // step3 scratch / np [16][32] (2048 B)
  // step-3 carving of sScr:
  float*    Pw   = sScr;                          // col-sum partials [4 waves][32 o] (512 B)
  _Float16* sUh  = (_Float16*)((unsigned char*)sScr + 512);   // u f16 [288] (576 B, 16B-aligned)
  _Float16* sVf  = (_Float16*)((unsigned char*)sScr + 1088);  // v f16 [32] (64 B, 16B-aligned)

  const int t   = threadIdx.x;
  const int l   = t & 63;
  const int wv  = t >> 6;
  const int bid = blockIdx.x;
  const int b   = bid / (HW * HW);
  const int sp  = bid % (HW * HW);
  const int hh  = sp / HW;
  const int ww  = sp % HW;

  H8U zu; zu.i2[0] = make_int2(0, 0); zu.i2[1] = make_int2(0, 0);
  const h8 zero8 = zu.v;

  // stage fp16 qf: sQtT[o][d] = fp16(w_next[o][d] * SCALE_L2E)   (256 h2 pairs, one pass)
  {
    const int o = t >> 3, dp = t & 7;
    const float a0 = w_next[o * 16 + 2 * dp]     * SCALE_L2E;
    const float a1 = w_next[o * 16 + 2 * dp + 1] * SCALE_L2E;
    *(h2*)(sQtT + o * 16 + 2 * dp) = pkrtz(a0, a1);
  }

  // ---- step 1: V[i][p*4+r] = sum_q pose[p][q]*w_current[q][r]; store f16 swizzled ----
  // swizzle: halves h of row i live at i*16 + 8*((h>>3) ^ ((i>>3)&1)) + (h&7)
  for (int i = t; i < NI; i += 256) {
    const int n = i / 9, kl = i % 9, ky = kl / 3, kx = kl % 3;
    const float* px = input + (((b * IN_N + n) * H_IN + (hh + ky)) * H_IN + (ww + kx)) * D;
    float p[16], wt[16];
    *(float4*)(p +  0) = *(const float4*)(px +  0);
    *(float4*)(p +  4) = *(const float4*)(px +  4);
    *(float4*)(p +  8) = *(const float4*)(px +  8);
    *(float4*)(p + 12) = *(const float4*)(px + 12);
    const float* wc = w_current + (kl * IN_N + n) * 16;
    *(float4*)(wt +  0) = *(const float4*)(wc +  0);
    *(float4*)(wt +  4) = *(const float4*)(wc +  4);
    *(float4*)(wt +  8) = *(const float4*)(wc +  8);
    *(float4*)(wt + 12) = *(const float4*)(wc + 12);
    float vv[16];
    #pragma unroll
    for (int pp = 0; pp < 4; ++pp)
      #pragma unroll
      for (int rr = 0; rr < 4; ++rr)
        vv[pp * 4 + rr] = p[pp*4+0]*wt[0+rr] + p[pp*4+1]*wt[4+rr]
                        + p[pp*4+2]*wt[8+rr] + p[pp*4+3]*wt[12+rr];
    H8U lo, hi;
    #pragma unroll
    for (int jj = 0; jj < 4; ++jj) {
      lo.q[jj] = pkrtz(vv[2*jj],     vv[2*jj + 1]);
      hi.q[jj] = pkrtz(vv[8 + 2*jj], vv[8 + 2*jj + 1]);
    }
    const int flip8 = ((i >> 3) & 1) * 8;
    *(h8*)(sVh + i * VH_S + flip8)       = lo.v;
    *(h8*)(sVh + i * VH_S + (flip8 ^ 8)) = hi.v;
  }
  __syncthreads();

  // ---- step 2: A^T[o][i] = exp2(Vf[i].qf_l2e[o]) via MFMA 16x16x32 (K zero-padded) ----
  {
    const int lo16 = l & 15;
    const int q4   = l >> 4;          // k-quad
    const int kq   = (q4 & 1) * 8;    // real k base for quads 0,1
    const bool hiK = (q4 >= 2);       // quads 2,3 = zero-pad region (k>=16)
    h8 bf[2];
    #pragma unroll
    for (int nt = 0; nt < 2; ++nt) {
      const int o = lo16 + 16 * nt;
      bf[nt] = hiK ? zero8 : *(const h8*)(sQtT + o * 16 + kq);   // halves kq..kq+7 of row o
    }
    const int vflip = 8 * ((q4 & 1) ^ ((lo16 >> 3) & 1));
    for (int mt = wv; mt < 18; mt += 4) {
      const int m = mt * 16 + lo16;
      h8 af = zero8;
      if (!hiK) af = *(const h8*)(sVh + m * VH_S + vflip);
      #pragma unroll
      for (int nt = 0; nt < 2; ++nt) {
        v4f acc = {0.f, 0.f, 0.f, 0.f};
        acc = __builtin_amdgcn_mfma_f32_16x16x32_f16(af, bf[nt], acc, 0, 0, 0);
        // D: col(o-within-tile)=l&15, row(i-offset)=4*q4+reg
        const int o  = lo16 + 16 * nt;
        const int ib = mt * 16 + 4 * q4;
        h2 p0 = pkrtz(exp2_fast(acc[0]), exp2_fast(acc[1]));
        h2 p1 = pkrtz(exp2_fast(acc[2]), exp2_fast(acc[3]));
        int2 wr; wr.x = h2bits(p0); wr.y = h2bits(p1);
        *(int2*)(sAt + o * AT_S + ib) = wr;   // A^T[o][ib..ib+3]
      }
    }
  }
  __syncthreads();

  // ---- step 3 + 5 shared A-fragments ----
  // The col-pass (and step 5) read sAt rows lo16 and lo16+16 at k-slices
  // kb0=wv*32+q4*8, kb1=(wv+4)*32+q4*8, kb2=(wv+8)*32+q4*8 (wv==0 only).
  // These are ITERATION-INVARIANT: hoist to registers once (6 x h8 = 24 VGPR),
  // reuse across all 7 Sinkhorn iterations AND step 5. This removes ~40
  // ds_read_b128/thread from the per-CU-shared LDS pipe (the measured limiter:
  // R9/R10 barrier+occupancy changes were null because LDS BW is per-CU).
  const int lo16 = l & 15;
  const int q4   = l >> 4;
  const int kb0 = wv * 32 + q4 * 8;
  const int kb1 = (wv + 4) * 32 + q4 * 8;
  const int kb2 = (wv + 8) * 32 + q4 * 8;   // in-range only for wv==0
  h8 caf00, caf01, caf10, caf11, caf20, caf21;
  {
    caf00 = *(const h8*)(sAt + lo16 * AT_S + kb0);
    caf01 = *(const h8*)(sAt + (16 + lo16) * AT_S + kb0);
    caf10 = *(const h8*)(sAt + lo16 * AT_S + kb1);
    caf11 = *(const h8*)(sAt + (16 + lo16) * AT_S + kb1);
    caf20 = zero8; caf21 = zero8;
    if (wv == 0) {   // wave-uniform branch
      caf20 = *(const h8*)(sAt + lo16 * AT_S + kb2);
      caf21 = *(const h8*)(sAt + (16 + lo16) * AT_S + kb2);
    }
  }

  // ---- step 3: Sinkhorn, minimum-VALU + minimum-LDS form, 2 barriers/iter ----
  {
    // preload A-row for row i=t (and i=t+32 for t>=224): strided u16 reads, one-time.
    // Arow[oo] = (A[i][2oo], A[i][2oo+1])
    h2 Arow[16];
    {
      const _Float16* colp = sAt + t;
      #pragma unroll
      for (int oo = 0; oo < 16; ++oo) {
        h2 a; a.x = colp[(2*oo) * AT_S]; a.y = colp[(2*oo + 1) * AT_S];
        Arow[oo] = a;
      }
    }
    h2 Arow2[16];
    if (t >= 224) {
      const _Float16* colp = sAt + (t + 32);
      #pragma unroll
      for (int oo = 0; oo < 16; ++oo) {
        h2 a; a.x = colp[(2*oo) * AT_S]; a.y = colp[(2*oo + 1) * AT_S];
        Arow2[oo] = a;
      }
    }

    for (int it = 0; it < ITERS; ++it) {
      // v fragments: v-pairs (v[2j],v[2j+1]); iter 0 = ones
      H8U va, vb, vc, vd;
      if (it == 0) {
        const h2 one2 = pkrtz(1.0f, 1.0f);
        #pragma unroll
        for (int jj = 0; jj < 4; ++jj) { va.q[jj] = one2; vb.q[jj] = one2; vc.q[jj] = one2; vd.q[jj] = one2; }
      } else {
        va.v = *(const h8*)(sVf);        // v[0..7]   (own-wave-written last iter)
        vb.v = *(const h8*)(sVf + 8);    // v[8..15]
        vc.v = *(const h8*)(sVf + 16);   // v[16..23]
        vd.v = *(const h8*)(sVf + 24);   // v[24..31]
      }
      // u-pass: row sums, fully in-lane (16 fdot2, fp32 accum)
      float s0 = 0.f, s1 = 0.f;
      #pragma unroll
      for (int oo = 0; oo < 4; ++oo) {
        s0 = dot2f(Arow[oo],      va.q[oo], s0);
        s0 = dot2f(Arow[4 + oo],  vb.q[oo], s0);
        s1 = dot2f(Arow[8 + oo],  vc.q[oo], s1);
        s1 = dot2f(Arow[12 + oo], vd.q[oo], s1);
      }
      const float u = __builtin_amdgcn_rcpf(s0 + s1);
      sUh[t] = (_Float16)u;
      if (t >= 224) {
        float e0 = 0.f, e1 = 0.f;
        #pragma unroll
        for (int oo = 0; oo < 4; ++oo) {
          e0 = dot2f(Arow2[oo],      va.q[oo], e0);
          e0 = dot2f(Arow2[4 + oo],  vb.q[oo], e0);
          e1 = dot2f(Arow2[8 + oo],  vc.q[oo], e1);
          e1 = dot2f(Arow2[12 + oo], vd.q[oo], e1);
        }
        const float u2 = __builtin_amdgcn_rcpf(e0 + e1);
        sUh[t + 32] = (_Float16)u2;
      }
      __syncthreads();   // BAR A: sUh complete

      // col-pass: acc[o] = sum_k A^T[o][k] u[k] on MFMA; A-frags from registers,
      // only the small broadcast u reads hit LDS.
      v4f acc0 = {0.f, 0.f, 0.f, 0.f};
      v4f acc1 = {0.f, 0.f, 0.f, 0.f};
      {
        const h8 uf0 = *(const h8*)(sUh + kb0);
        acc0 = __builtin_amdgcn_mfma_f32_16x16x32_f16(caf00, uf0, acc0, 0, 0, 0);
        acc1 = __builtin_amdgcn_mfma_f32_16x16x32_f16(caf01, uf0, acc1, 0, 0, 0);
        const h8 uf1 = *(const h8*)(sUh + kb1);
        acc0 = __builtin_amdgcn_mfma_f32_16x16x32_f16(caf10, uf1, acc0, 0, 0, 0);
        acc1 = __builtin_amdgcn_mfma_f32_16x16x32_f16(caf11, uf1, acc1, 0, 0, 0);
        if (wv == 0) {   // wave-uniform
          const h8 uf2 = *(const h8*)(sUh + kb2);
          acc0 = __builtin_amdgcn_mfma_f32_16x16x32_f16(caf20, uf2, acc0, 0, 0, 0);
          acc1 = __builtin_amdgcn_mfma_f32_16x16x32_f16(caf21, uf2, acc1, 0, 0, 0);
        }
      }
      // D cols all equal; rows o = tile*16 + 4*q4 + reg. One lane-group writes.
      if (lo16 == 0) {
        *(v4f*)(Pw + wv * 32 + 0  + 4 * q4) = acc0;
        *(v4f*)(Pw + wv * 32 + 16 + 4 * q4) = acc1;
      }
      __syncthreads();   // BAR B: Pw complete (also: all sUh reads done)

      // v-finalize, ALL lanes (o covered twice per wave; dup writes identical)
      {
        const int o = l & 31;
        const float S = Pw[0 * 32 + o] + Pw[1 * 32 + o] + Pw[2 * 32 + o] + Pw[3 * 32 + o];
        const float v = 8.0f * __builtin_amdgcn_rcpf(S);
        sVf[o] = (_Float16)v;
        if (it == ITERS - 1 && t < 32) sUv[o] = v;   // fp32 final v for the combine
      }
      // no BAR C: next u-pass reads sVf this wave just wrote (lgkmcnt orders it)
    }
  }

  // ---- step 5: np~[o][d] = sum_k (A^T[o][k]*u_k) * V[k][d] via MFMA 16x16x32 ----
  // A-fragments reused from the hoisted registers (d == lo16 -> same addresses);
  // u folded into A with v_pk_mul_f16; B is raw f16 pair-assembly from sVh.
  v4f acc5_0 = {0.f, 0.f, 0.f, 0.f};
  v4f acc5_1 = {0.f, 0.f, 0.f, 0.f};
  {
    const int d = lo16;
    // swizzled half offset for column d of row r: 8*((d>>3) ^ ((r>>3)&1)) + (d&7);
    // (r>>3)&1 == q4&1 for all rows r = kt*32 + q4*8 + z (z<8) -> per-lane constant
    const int doff = 8 * ((d >> 3) ^ (q4 & 1)) + (d & 7);
    #pragma unroll
    for (int slot = 0; slot < 3; ++slot) {
      if (slot == 2 && wv != 0) break;   // wave-uniform
      const int kg = (slot == 0) ? kb0 : (slot == 1) ? kb1 : kb2;
      const h8 ca0 = (slot == 0) ? caf00 : (slot == 1) ? caf10 : caf20;
      const h8 ca1 = (slot == 0) ? caf01 : (slot == 1) ? caf11 : caf21;
      H8U uu; uu.v = *(const h8*)(sUh + kg);                 // u[kg..kg+7] f16 (broadcast)
      H8U a0; a0.v = ca0;
      H8U a1; a1.v = ca1;
      H8U a0u, a1u;
      #pragma unroll
      for (int jj = 0; jj < 4; ++jj) {
        a0u.q[jj] = a0.q[jj] * uu.q[jj];                     // v_pk_mul_f16
        a1u.q[jj] = a1.q[jj] * uu.q[jj];
      }
      H8U bu;
      #pragma unroll
      for (int jj = 0; jj < 4; ++jj) {
        h2 bq;
        bq.x = sVh[(kg + 2*jj)     * VH_S + doff];
        bq.y = sVh[(kg + 2*jj + 1) * VH_S + doff];
        bu.q[jj] = bq;
      }
      acc5_0 = __builtin_amdgcn_mfma_f32_16x16x32_f16(a0u.v, bu.v, acc5_0, 0, 0, 0);
      acc5_1 = __builtin_amdgcn_mfma_f32_16x16x32_f16(a1u.v, bu.v, acc5_1, 0, 0, 0);
    }
  }
  __syncthreads();   // all sVh/sAt/sUh reads done -> safe to overlay P into sVh
  {
    const int d = lo16;
    // D: col=d, row(o-offset)=4*q4+reg
    *(v4f*)(Pf + (wv * 16 + d) * P_S + 0  + 4 * q4) = acc5_0;
    *(v4f*)(Pf + (wv * 16 + d) * P_S + 16 + 4 * q4) = acc5_1;
  }
  __syncthreads();
  // combine K-partials: sScr = np*3*ln2 = S~ * v~_o * (3/8)*ln2.
  // (the /8 undoes the v rescale; ln2 cancels sQtT's log2e in step 6 EXACTLY)
  #pragma unroll
  for (int pass = 0; pass < 2; ++pass) {
    const int e = t + 256 * pass;
    const int o = e & 31, dd = e >> 5;
    const float S = Pf[(0 * 16 + dd) * P_S + o] + Pf[(1 * 16 + dd) * P_S + o]
                  + Pf[(2 * 16 + dd) * P_S + o] + Pf[(3 * 16 + dd) * P_S + o];
    sScr[dd * 32 + o] = S * COMB_C * sUv[o];
  }
  __syncthreads();

  // ---- step 6: out[o][p*4+r] = sum_q np[o][p*4+q]*w_next[o][q*4+r]; LayerNorm over d ----
  // np*3*ln2 times w_next*(log2e/3) == np*w_next exactly -> EPS-consistent LN.
  {
    float vals[2];
    #pragma unroll
    for (int h2p = 0; h2p < 2; ++h2p) {
      const int e = t + h2p * 256;
      const int o = e >> 4, dd = e & 15;
      const int pp = dd >> 2, rr = dd & 3;
      float acc = 0.f;
      #pragma unroll
      for (int q = 0; q < 4; ++q)
        acc += sScr[(pp * 4 + q) * 32 + o] * (float)sQtT[o * 16 + q * 4 + rr];
      vals[h2p] = acc;
    }
    // LN over the 16 d's: full-16 DPP reduction (quad sums, then rotate-4/8)
    float s0 = vals[0], q0 = vals[0] * vals[0];
    float s1 = vals[1], q1 = vals[1] * vals[1];
    s0 = dpp_add<DPP_XOR1>(s0); q0 = dpp_add<DPP_XOR1>(q0);
    s1 = dpp_add<DPP_XOR1>(s1); q1 = dpp_add<DPP_XOR1>(q1);
    s0 = dpp_add<DPP_XOR2>(s0); q0 = dpp_add<DPP_XOR2>(q0);
    s1 = dpp_add<DPP_XOR2>(s1); q1 = dpp_add<DPP_XOR2>(q1);
    s0 = dpp_add<DPP_ROR4>(s0); q0 = dpp_add<DPP_ROR4>(q0);
    s1 = dpp_add<DPP_ROR4>(s1); q1 = dpp_add<DPP_ROR4>(q1);
    s0 = dpp_add<DPP_ROR8>(s0); q0 = dpp_add<DPP_ROR8>(q0);
    s1 = dpp_add<DPP_ROR8>(s1); q1 = dpp_add<DPP_ROR8>(q1);
    #pragma unroll
    for (int h2p = 0; h2p < 2; ++h2p) {
      const int e = t + h2p * 256;
      const int o = e >> 4, dd = e & 15;
      const float ss = h2p ? s1 : s0;
      const float qq = h2p ? q1 : q0;
      const float mu   = ss * (1.0f / 16.0f);
      const float var  = qq * (1.0f / 16.0f) - mu * mu;
      const float rstd = rsqrtf(var + EPS);
      const float y = (vals[h2p] - mu) * rstd * ln_scale[dd] + ln_bias[dd];
      out[(((b * OUT_N + o) * HW + hh) * HW + ww) * D + dd] = y;
    }
  }
}

extern "C" void kernel_launch(void* const* d_in, const int* in_sizes, int n_in,
                              void* d_out, int out_size, void* d_ws, size_t ws_size,
                              hipStream_t stream) {
  const float* input     = (const float*)d_in[0];
  const float* w_current = (const float*)d_in[1];
  const float* w_next    = (const float*)d_in[2];
  const float* ln_scale  = (const float*)d_in[3];
  const float* ln_bias   = (const float*)d_in[4];
  float* outp = (float*)d_out;

  dim3 grid(BATCH * HW * HW);   // 2704 blocks, one per (b, h, w)
  dim3 block(256);
  capsule_fused<<<grid, block, 0, stream>>>(input, w_current, w_next,
                                            ln_scale, ln_bias, outp);
}